// Round 5
// baseline (1073.581 us; speedup 1.0000x reference)
//
#include <hip/hip_runtime.h>

typedef __attribute__((ext_vector_type(8))) short short8;
typedef __attribute__((ext_vector_type(4))) float float4v;
typedef __attribute__((ext_vector_type(4))) unsigned short ushort4v;

#define DEV __device__ __forceinline__
#define AGENT __HIP_MEMORY_SCOPE_AGENT

DEV unsigned short f2bf(float f) {
  union { float f; unsigned u; } v; v.f = f;
  unsigned r = v.u + 0x7fffu + ((v.u >> 16) & 1u);
  return (unsigned short)(r >> 16);
}
DEV float bf2f(unsigned short h) {
  union { unsigned u; float f; } v; v.u = ((unsigned)h) << 16;
  return v.f;
}

// async global->LDS, 16B per lane; LDS dest is wave-uniform base + lane*16
DEV void gl2lds16(const void* g, void* l) {
  __builtin_amdgcn_global_load_lds(
      (const __attribute__((address_space(1))) void*)g,
      (__attribute__((address_space(3))) void*)l, 16, 0, 0);
}

// --- cross-workgroup data movement: LLC write-through / bypass ------------
DEV void ast32(unsigned short* p, unsigned v) {
  __hip_atomic_store((unsigned*)p, v, __ATOMIC_RELAXED, AGENT);
}
DEV short8 ald16(const unsigned short* p) {
  unsigned long long lo = __hip_atomic_load((const unsigned long long*)p,     __ATOMIC_RELAXED, AGENT);
  unsigned long long hi = __hip_atomic_load((const unsigned long long*)p + 1, __ATOMIC_RELAXED, AGENT);
  union { unsigned long long q[2]; short8 s; } u;
  u.q[0] = lo; u.q[1] = hi;
  return u.s;
}

// Grid barrier without RMW: wg stores flags[wg]=epoch (own cacheline);
// wave0's 64 lanes each poll one wg's flag, __all across the wave.
// __syncthreads before = vmcnt(0) drain (stores are write-through, at LLC).
DEV void bar(unsigned* flags, unsigned epoch) {
  __syncthreads();
  if (threadIdx.x < 64) {
    const int lane = threadIdx.x;
    if (lane == 0)
      __hip_atomic_store(&flags[blockIdx.x * 32], epoch, __ATOMIC_RELAXED, AGENT);
    bool ok = false;
    do {
      ok = ok || (__hip_atomic_load(&flags[lane * 32], __ATOMIC_RELAXED, AGENT) >= epoch);
    } while (!__all(ok));
  }
  __syncthreads();
}

__global__ __launch_bounds__(256) void zero_flags(unsigned* p, int n) {
  int i = blockIdx.x * 256 + threadIdx.x;
  if (i < n) p[i] = 0;
}

// ---------------------------------------------------------------------------
// fp32 -> bf16 convert, 4 elems/thread
__global__ __launch_bounds__(256) void cvt4(const float* __restrict__ in,
                                            unsigned short* __restrict__ out, int n4) {
  const int idx = blockIdx.x * 256 + threadIdx.x;
  if (idx >= n4) return;
  float4 v = ((const float4*)in)[idx];
  ushort4v o = { f2bf(v.x), f2bf(v.y), f2bf(v.z), f2bf(v.w) };
  ((ushort4v*)out)[idx] = o;
}

// ---------------------------------------------------------------------------
// Gather X[row] = [emb(kw_{i+1}) | emb(lw_i)] as bf16, row = i*32+b
__global__ __launch_bounds__(256) void gatherx(const float* __restrict__ emb,
                                               const int* __restrict__ targets,
                                               const int* __restrict__ tkws,
                                               unsigned short* __restrict__ X) {
  const int row = blockIdx.x;
  const int i = row >> 5, b = row & 31;
  const int t = threadIdx.x;
  const int kw = tkws[b * 64 + i + 1];
  const int lw = targets[b * 64 + i];
  const float4* src = (t < 128) ? (const float4*)(emb + (size_t)kw * 512)
                                : (const float4*)(emb + (size_t)lw * 512);
  const int c = t & 127;
  float4 v = src[c];
  ushort4v o = { f2bf(v.x), f2bf(v.y), f2bf(v.z), f2bf(v.w) };
  ((ushort4v*)(X + (size_t)row * 1024))[(t < 128 ? 0 : 128) + c] = o;
}

// ---------------------------------------------------------------------------
// C = A[M,1024] * B[N,1024]^T, 128x128 tile, BK=32, bf16 MFMA 16x16x32.
// fp32 C store (used for the Gi pre-GEMM only).
__global__ __launch_bounds__(256, 1) void gemm_bt0(
    const unsigned short* __restrict__ A,
    const unsigned short* __restrict__ B,
    float* __restrict__ out,
    int ldc) {
  __shared__ __align__(16) unsigned short As[128 * 32];
  __shared__ __align__(16) unsigned short Bs[128 * 32];
  const int tid = threadIdx.x;
  const int w = tid >> 6, lane = tid & 63;
  const int r4 = lane >> 2, c4 = lane & 3;
  const int m0 = blockIdx.x * 128, n0 = blockIdx.y * 128;
  const int m_off = (w & 1) * 64, n_off = (w >> 1) * 64;
  const int lrow = lane & 15, lk = (lane >> 4) * 8;

  const unsigned short* Ab = A + (size_t)(m0 + w * 16 + r4) * 1024 + c4 * 8;
  const unsigned short* Bb = B + (size_t)(n0 + w * 16 + r4) * 1024 + c4 * 8;

  float4v acc[4][4] = {};

  for (int k0 = 0; k0 < 1024; k0 += 32) {
    gl2lds16(Ab + k0,             &As[w * 512]);
    gl2lds16(Ab + 64 * 1024 + k0, &As[2048 + w * 512]);
    gl2lds16(Bb + k0,             &Bs[w * 512]);
    gl2lds16(Bb + 64 * 1024 + k0, &Bs[2048 + w * 512]);
    __syncthreads();
    short8 af[4], bfr[4];
#pragma unroll
    for (int t = 0; t < 4; t++) {
      af[t]  = *(const short8*)&As[(m_off + t * 16 + lrow) * 32 + lk];
      bfr[t] = *(const short8*)&Bs[(n_off + t * 16 + lrow) * 32 + lk];
    }
#pragma unroll
    for (int mt = 0; mt < 4; mt++)
#pragma unroll
      for (int nt = 0; nt < 4; nt++)
        acc[mt][nt] = __builtin_amdgcn_mfma_f32_16x16x32_bf16(af[mt], bfr[nt], acc[mt][nt], 0, 0, 0);
    __syncthreads();
  }

#pragma unroll
  for (int mt = 0; mt < 4; mt++) {
    const int gr = m0 + m_off + mt * 16 + (lane >> 4) * 4;
#pragma unroll
    for (int nt = 0; nt < 4; nt++) {
      const int gc = n0 + n_off + nt * 16 + lrow;
#pragma unroll
      for (int rg = 0; rg < 4; rg++)
        out[(size_t)(gr + rg) * ldc + gc] = acc[mt][nt][rg];
    }
  }
}

// ---------------------------------------------------------------------------
// Fused kernel, NORMAL launch, grid 256 x 256thr. 117KB static LDS forces
// 1 wg/CU; grid == #CUs, so all wgs are co-resident without the cooperative
// API (a CU holds at most one wg, and there are as many CUs as wgs).
//   wgs 0..63   : recurrence (identical to the R2-passing structure).
//   wgs 64..255 : (a) out_W fp32->bf16 (agent-scope write-through),
//                 (b) 192-wg flag barrier, (c) logits GEMM M=2048 N=32000,
//                 each 128-row M-tile gated on the recur epoch flags.
// All cross-wg data (WH, outWb, h/sent, flags) is written with agent-scope
// atomic stores and read with agent-scope atomic loads (ald16) -> LLC
// coherent by construction, no reliance on L1/L2 invalidation.
// Epoch math: WH rows of step i are LLC-visible once all 64 recur flags
// reach E(i) = 2 + i + popc(eosmask & ((1<<i)-1)). GEMM wgs never block the
// recur wgs -> no deadlock.
__global__ __launch_bounds__(256, 1) void fused_kernel(
    const float* __restrict__ Gi,
    const unsigned short* __restrict__ WhhB,
    const unsigned short* __restrict__ sWihB,
    const unsigned short* __restrict__ sWhhB,
    unsigned short* __restrict__ h_bf,      // 2 x 32768 u16
    unsigned short* __restrict__ sent_bf,   // 2 x 32768 u16
    unsigned short* __restrict__ WH,
    const float* __restrict__ w_bih, const float* __restrict__ w_bhh,
    const float* __restrict__ s_bih, const float* __restrict__ s_bhh,
    const int* __restrict__ targets,
    const float* __restrict__ sent_state,
    unsigned* __restrict__ flags,           // [64*32] recur epochs
    unsigned* __restrict__ gflags,          // [192*32] cvt barrier
    const float* __restrict__ outW,
    unsigned short* __restrict__ outWb,
    float* __restrict__ parts,              // float2 [2048][250]
    const float* __restrict__ out_b) {
  __shared__ __align__(16) unsigned char smem[117248];
  const int tid = threadIdx.x;
  const int lane = tid & 63, wv = tid >> 6;

  // per-wave "any EOS at step i" bitmask (grid-uniform, both sides need it)
  unsigned long long eosmask;
  {
    bool e = false;
    if (lane < 63)
      for (int b = 0; b < 32; b++) e |= (targets[b * 64 + lane + 1] == 1);
    eosmask = __ballot(e);
  }

  if (blockIdx.x >= 64) {
    // ==================== GEMM side (192 wgs) ====================
    const int wg = blockIdx.x - 64;
    unsigned short* As = (unsigned short*)smem;            //  8 KB
    unsigned short* Bs = (unsigned short*)(smem + 8192);   //  8 KB
    float*          msb = (float*)(smem + 16384);          //  2 KB [2][128][2]

    // (a) out_W -> bf16, write-through so other XCDs see it
    for (int idx = wg * 256 + tid; idx < 8192000; idx += 192 * 256) {
      float4 v = ((const float4*)outW)[idx];
      unsigned p0 = (unsigned)f2bf(v.x) | ((unsigned)f2bf(v.y) << 16);
      unsigned p1 = (unsigned)f2bf(v.z) | ((unsigned)f2bf(v.w) << 16);
      unsigned long long pq = (unsigned long long)p0 | ((unsigned long long)p1 << 32);
      __hip_atomic_store((unsigned long long*)&outWb[(size_t)idx * 4], pq,
                         __ATOMIC_RELAXED, AGENT);
    }
    // (b) one-shot barrier among the 192 GEMM wgs
    __syncthreads();                       // drains the write-through stores
    if (tid == 0)
      __hip_atomic_store(&gflags[wg * 32], 1u, __ATOMIC_RELAXED, AGENT);
    if (tid < 64) {
      bool o0 = false, o1 = false, o2 = false;
      while (true) {
        o0 = o0 || (__hip_atomic_load(&gflags[tid * 32],         __ATOMIC_RELAXED, AGENT) != 0u);
        o1 = o1 || (__hip_atomic_load(&gflags[(64 + tid) * 32],  __ATOMIC_RELAXED, AGENT) != 0u);
        o2 = o2 || (__hip_atomic_load(&gflags[(128 + tid) * 32], __ATOMIC_RELAXED, AGENT) != 0u);
        if (__all(o0 && o1 && o2)) break;
        __builtin_amdgcn_s_sleep(32);
      }
    }
    __syncthreads();

    // (c) logits GEMM, 4000 blocks grid-strided m-major (mt nondecreasing
    // per wg => gates hit in increasing-epoch order, usually pre-passed)
    const int w = wv;
    const int r4 = lane >> 2, c4 = lane & 3;
    const int lrow = lane & 15, lk = (lane >> 4) * 8;
    const int m_off = (w & 1) * 64, n_off = (w >> 1) * 64;
    int gated_mt = -1;
    for (int bi = wg; bi < 4000; bi += 192) {
      const int mt = bi / 250, nt = bi - mt * 250;
      if (mt > gated_mt) {
        const int L = (4 * mt + 3 > 62) ? 62 : (4 * mt + 3);
        const unsigned E = 2u + (unsigned)L +
            (unsigned)__popcll(eosmask & ((1ull << L) - 1ull));
        if (tid < 64) {
          bool ok = false;
          while (true) {
            ok = ok || (__hip_atomic_load(&flags[tid * 32], __ATOMIC_RELAXED, AGENT) >= E);
            if (__all(ok)) break;
            __builtin_amdgcn_s_sleep(32);
          }
        }
        __syncthreads();
        gated_mt = mt;
      }
      const int m0 = mt * 128, n0 = nt * 128;
      const unsigned short* Ab = WH    + (size_t)(m0 + w * 16 + r4) * 1024 + c4 * 8;
      const unsigned short* Bb = outWb + (size_t)(n0 + w * 16 + r4) * 1024 + c4 * 8;
      float4v acc[4][4] = {};
      for (int k0 = 0; k0 < 1024; k0 += 32) {
        // stage via LLC-coherent atomic loads (WH/outWb are cross-wg data)
        short8 va0 = ald16(Ab + k0);
        short8 va1 = ald16(Ab + 64 * 1024 + k0);
        short8 vb0 = ald16(Bb + k0);
        short8 vb1 = ald16(Bb + 64 * 1024 + k0);
        *(short8*)&As[w * 512 + lane * 8]        = va0;
        *(short8*)&As[2048 + w * 512 + lane * 8] = va1;
        *(short8*)&Bs[w * 512 + lane * 8]        = vb0;
        *(short8*)&Bs[2048 + w * 512 + lane * 8] = vb1;
        __syncthreads();
        short8 af[4], bfr[4];
#pragma unroll
        for (int t = 0; t < 4; t++) {
          af[t]  = *(const short8*)&As[(m_off + t * 16 + lrow) * 32 + lk];
          bfr[t] = *(const short8*)&Bs[(n_off + t * 16 + lrow) * 32 + lk];
        }
#pragma unroll
        for (int a = 0; a < 4; a++)
#pragma unroll
          for (int b = 0; b < 4; b++)
            acc[a][b] = __builtin_amdgcn_mfma_f32_16x16x32_bf16(af[a], bfr[b], acc[a][b], 0, 0, 0);
        __syncthreads();
      }
      // epilogue: bias + per-row (max, sum-exp) over this 128-col tile
      float b4[4];
#pragma unroll
      for (int b = 0; b < 4; b++) b4[b] = out_b[n0 + n_off + b * 16 + lrow];
#pragma unroll
      for (int a = 0; a < 4; a++) {
#pragma unroll
        for (int rg = 0; rg < 4; rg++) {
          float v0 = acc[a][0][rg] + b4[0];
          float v1 = acc[a][1][rg] + b4[1];
          float v2 = acc[a][2][rg] + b4[2];
          float v3 = acc[a][3][rg] + b4[3];
          float mx = fmaxf(fmaxf(v0, v1), fmaxf(v2, v3));
#pragma unroll
          for (int d = 1; d < 16; d <<= 1) mx = fmaxf(mx, __shfl_xor(mx, d, 64));
          float s = __expf(v0 - mx) + __expf(v1 - mx) + __expf(v2 - mx) + __expf(v3 - mx);
#pragma unroll
          for (int d = 1; d < 16; d <<= 1) s += __shfl_xor(s, d, 64);
          if ((lane & 15) == 0) {
            int r = m_off + a * 16 + (lane >> 4) * 4 + rg;
            msb[(w >> 1) * 256 + r * 2 + 0] = mx;
            msb[(w >> 1) * 256 + r * 2 + 1] = s;
          }
        }
      }
      __syncthreads();
      if (tid < 128) {
        float m1 = msb[tid * 2], s1 = msb[tid * 2 + 1];
        float m2 = msb[256 + tid * 2], s2 = msb[256 + tid * 2 + 1];
        float M = fmaxf(m1, m2);
        float S = s1 * __expf(m1 - M) + s2 * __expf(m2 - M);
        ((float2*)parts)[(size_t)(m0 + tid) * 250 + nt] = make_float2(M, S);
      }
      __syncthreads();
    }
    return;
  }

  // ==================== recur side (64 wgs) ====================
  unsigned short* WhhS = (unsigned short*)smem;                  // 96 KB
  float (*Cred)[32][49] = (float (*)[32][49])(smem + 98304);     // 12544 B
  float (*hsl)[16] = (float (*)[16])(smem + 110848);             // 2 KB
  float (*ssl)[16] = (float (*)[16])(smem + 112896);             // 2 KB
  float (*whsl)[16] = (float (*)[16])(smem + 114944);            // 2 KB

  const int khalf = wv >> 1, mtile = wv & 1;
  const int jb = blockIdx.x * 16;
  const int lr = lane & 15;
  const int bb = mtile * 16 + lr;
  const int kb = khalf * 512 + (lane >> 4) * 8;
  const int cb = kb >> 3;          // 16B-chunk base within row
  const int swz = lr & 7;
  const int b0 = (tid * 2) >> 4, j0 = (tid * 2) & 15;
  unsigned epoch = 0;
  int scur = 0;

  // ---- one-time: Whh wg-slice -> LDS, XOR-swizzled 16B chunks ----
  for (int idx = tid; idx < 6144; idx += 256) {
    const int R = idx >> 7, c = idx & 127;     // R = g*16+rr, c = chunk
    const int g = R >> 4, rr = R & 15;
    short8 v = *(const short8*)&WhhB[((size_t)(g * 1024 + jb + rr)) * 1024 + c * 8];
    *(short8*)&WhhS[(R * 128 + (c ^ (rr & 7))) * 8] = v;
  }

  // ---- one-time: biases for this thread's 2 elements ----
  float bi[2][3], bh[2][3];
#pragma unroll
  for (int u = 0; u < 2; u++)
#pragma unroll
    for (int g = 0; g < 3; g++) {
      bi[u][g] = w_bih[g * 1024 + jb + j0 + u];
      bh[u][g] = w_bhh[g * 1024 + jb + j0 + u];
    }

  // ---- init state, publish to buffer 0 ----
  {
    float v0 = sent_state[b0 * 1024 + jb + j0];
    float v1 = sent_state[b0 * 1024 + jb + j0 + 1];
    hsl[b0][j0] = v0; hsl[b0][j0 + 1] = v1;
    ssl[b0][j0] = v0; ssl[b0][j0 + 1] = v1;
    unsigned pv = (unsigned)f2bf(v0) | ((unsigned)f2bf(v1) << 16);
    ast32(&h_bf[b0 * 1024 + jb + j0], pv);
    ast32(&sent_bf[b0 * 1024 + jb + j0], pv);
  }

  // ---- Gi prefetch for step 0 ----
  float2 gp[3];
  {
    const float* p = Gi + (size_t)b0 * 3072 + jb + j0;
    gp[0] = *(const float2*)(p);
    gp[1] = *(const float2*)(p + 1024);
    gp[2] = *(const float2*)(p + 2048);
  }

  epoch++; bar(flags, epoch);

  for (int i = 0; i < 63; i++) {
    const unsigned short* hr = h_bf + (i & 1) * 32768;
    unsigned short*       hw = h_bf + ((i + 1) & 1) * 32768;
    const bool anyeos = (eosmask >> i) & 1;

    // gh = h @ Whh^T  (A from LLC, B from LDS); batch-issue coherent loads
    short8 a[16];
#pragma unroll
    for (int ks = 0; ks < 16; ks++)
      a[ks] = ald16(&hr[bb * 1024 + kb + ks * 32]);
    float4v acc[3] = {};
#pragma unroll
    for (int ks = 0; ks < 16; ks++) {
#pragma unroll
      for (int g = 0; g < 3; g++) {
        short8 b8 = *(const short8*)&WhhS[((g * 16 + lr) * 128 + ((cb + ks * 4) ^ swz)) * 8];
        acc[g] = __builtin_amdgcn_mfma_f32_16x16x32_bf16(a[ks], b8, acc[g], 0, 0, 0);
      }
    }
#pragma unroll
    for (int g = 0; g < 3; g++)
#pragma unroll
      for (int rg = 0; rg < 4; rg++)
        Cred[khalf][mtile * 16 + (lane >> 4) * 4 + rg][g * 16 + lr] = acc[g][rg];
    __syncthreads();

    float wh2[2];
#pragma unroll
    for (int u = 0; u < 2; u++) {
      const int jj = j0 + u;
      float ghr = Cred[0][b0][jj]      + Cred[1][b0][jj]      + bh[u][0];
      float ghz = Cred[0][b0][16 + jj] + Cred[1][b0][16 + jj] + bh[u][1];
      float ghn = Cred[0][b0][32 + jj] + Cred[1][b0][32 + jj] + bh[u][2];
      float gir = ((float*)&gp[0])[u] + bi[u][0];
      float giz = ((float*)&gp[1])[u] + bi[u][1];
      float gin = ((float*)&gp[2])[u] + bi[u][2];
      float r = 1.f / (1.f + __expf(-(gir + ghr)));
      float z = 1.f / (1.f + __expf(-(giz + ghz)));
      float n = tanhf(gin + r * ghn);
      float wh = (1.f - z) * n + z * hsl[b0][jj];
      whsl[b0][jj] = wh;
      wh2[u] = wh;
    }
    {
      unsigned pv = (unsigned)f2bf(wh2[0]) | ((unsigned)f2bf(wh2[1]) << 16);
      ast32(&WH[(size_t)(i * 32 + b0) * 1024 + jb + j0], pv);
    }

    // Gi prefetch for next step (independent of barrier)
    if (i < 62) {
      const float* p = Gi + (size_t)((i + 1) * 32 + b0) * 3072 + jb + j0;
      gp[0] = *(const float2*)(p);
      gp[1] = *(const float2*)(p + 1024);
      gp[2] = *(const float2*)(p + 2048);
    }

    if (!anyeos) {
      hsl[b0][j0] = wh2[0]; hsl[b0][j0 + 1] = wh2[1];
      unsigned pv = (unsigned)f2bf(wh2[0]) | ((unsigned)f2bf(wh2[1]) << 16);
      ast32(&hw[b0 * 1024 + jb + j0], pv);
      epoch++; bar(flags, epoch);
    } else {
      epoch++; bar(flags, epoch);   // WH[i] visible grid-wide
      const unsigned short* sr = sent_bf + scur * 32768;
      unsigned short*       sw = sent_bf + (scur ^ 1) * 32768;
      // gi_s = wh @ sWih^T  (batch-issued coherent A-loads)
      short8 a2[16];
#pragma unroll
      for (int ks = 0; ks < 16; ks++)
        a2[ks] = ald16(&WH[(size_t)(i * 32 + bb) * 1024 + kb + ks * 32]);
      float4v acc2[3] = {};
#pragma unroll
      for (int ks = 0; ks < 16; ks++) {
#pragma unroll
        for (int g = 0; g < 3; g++) {
          short8 b8 = *(const short8*)&sWihB[(size_t)(g * 1024 + jb + lr) * 1024 + kb + ks * 32];
          acc2[g] = __builtin_amdgcn_mfma_f32_16x16x32_bf16(a2[ks], b8, acc2[g], 0, 0, 0);
        }
      }
#pragma unroll
      for (int g = 0; g < 3; g++)
#pragma unroll
        for (int rg = 0; rg < 4; rg++)
          Cred[khalf][mtile * 16 + (lane >> 4) * 4 + rg][g * 16 + lr] = acc2[g][rg];
      __syncthreads();
      float gis[2][3];
#pragma unroll
      for (int u = 0; u < 2; u++) {
        const int jj = j0 + u;
#pragma unroll
        for (int g = 0; g < 3; g++)
          gis[u][g] = Cred[0][b0][g * 16 + jj] + Cred[1][b0][g * 16 + jj] + s_bih[g * 1024 + jb + jj];
      }
      __syncthreads();
      // gh_s = sent @ sWhh^T  (batch-issued coherent A-loads)
      short8 a3[16];
#pragma unroll
      for (int ks = 0; ks < 16; ks++)
        a3[ks] = ald16(&sr[bb * 1024 + kb + ks * 32]);
      float4v acc3[3] = {};
#pragma unroll
      for (int ks = 0; ks < 16; ks++) {
#pragma unroll
        for (int g = 0; g < 3; g++) {
          short8 b8 = *(const short8*)&sWhhB[(size_t)(g * 1024 + jb + lr) * 1024 + kb + ks * 32];
          acc3[g] = __builtin_amdgcn_mfma_f32_16x16x32_bf16(a3[ks], b8, acc3[g], 0, 0, 0);
        }
      }
#pragma unroll
      for (int g = 0; g < 3; g++)
#pragma unroll
        for (int rg = 0; rg < 4; rg++)
          Cred[khalf][mtile * 16 + (lane >> 4) * 4 + rg][g * 16 + lr] = acc3[g][rg];
      __syncthreads();
      float ns2[2], nw2[2];
#pragma unroll
      for (int u = 0; u < 2; u++) {
        const int jj = j0 + u;
        float shr = Cred[0][b0][jj]      + Cred[1][b0][jj]      + s_bhh[jb + jj];
        float shz = Cred[0][b0][16 + jj] + Cred[1][b0][16 + jj] + s_bhh[1024 + jb + jj];
        float shn = Cred[0][b0][32 + jj] + Cred[1][b0][32 + jj] + s_bhh[2048 + jb + jj];
        float r = 1.f / (1.f + __expf(-(gis[u][0] + shr)));
        float z = 1.f / (1.f + __expf(-(gis[u][1] + shz)));
        float n = tanhf(gis[u][2] + r * shn);
        float s_old = ssl[b0][jj];
        float tmp = (1.f - z) * n + z * s_old;
        bool m = (targets[b0 * 64 + i + 1] == 1);
        ns2[u] = m ? tmp : s_old;
        nw2[u] = m ? tmp : whsl[b0][jj];
        ssl[b0][jj] = ns2[u];
        hsl[b0][jj] = nw2[u];
      }
      unsigned pvs = (unsigned)f2bf(ns2[0]) | ((unsigned)f2bf(ns2[1]) << 16);
      unsigned pvh = (unsigned)f2bf(nw2[0]) | ((unsigned)f2bf(nw2[1]) << 16);
      ast32(&sw[b0 * 1024 + jb + j0], pvs);
      ast32(&hw[b0 * 1024 + jb + j0], pvh);
      scur ^= 1;
      epoch++; bar(flags, epoch);
    }
  }
}

// ---------------------------------------------------------------------------
// Per row: y = WH[row].outW[tgt] + out_b[tgt]; lse from 250 (m,s) partials;
// term = valid * (y - lse). One wave per row.
__global__ __launch_bounds__(256) void row_loss(
    const unsigned short* __restrict__ WH,
    const unsigned short* __restrict__ outWb,
    const float* __restrict__ out_b,
    const int* __restrict__ targets,
    const int* __restrict__ targets_len,
    const float2* __restrict__ partials,
    float* __restrict__ term) {
  const int wv = threadIdx.x >> 6, lane = threadIdx.x & 63;
  const int row = blockIdx.x * 4 + wv;
  const int b = row & 31, i = row >> 5;
  const int tgt = targets[b * 64 + i + 1];
  const short8* a8 = (const short8*)(WH + (size_t)row * 1024);
  const short8* w8 = (const short8*)(outWb + (size_t)tgt * 1024);
  float s = 0.f;
#pragma unroll
  for (int c = 0; c < 2; c++) {
    short8 av = a8[lane + 64 * c];
    short8 wv8 = w8[lane + 64 * c];
#pragma unroll
    for (int j = 0; j < 8; j++)
      s += bf2f((unsigned short)av[j]) * bf2f((unsigned short)wv8[j]);
  }
#pragma unroll
  for (int d = 32; d; d >>= 1) s += __shfl_xor(s, d, 64);

  float m = -1e30f, ssum = 0.f;
  for (int vt = lane; vt < 250; vt += 64) {
    float2 pp = partials[(size_t)row * 250 + vt];
    float nm = fmaxf(m, pp.x);
    ssum = ssum * __expf(m - nm) + pp.y * __expf(pp.x - nm);
    m = nm;
  }
#pragma unroll
  for (int d = 32; d; d >>= 1) {
    float om = __shfl_xor(m, d, 64);
    float os = __shfl_xor(ssum, d, 64);
    float nm = fmaxf(m, om);
    ssum = ssum * __expf(m - nm) + os * __expf(om - nm);
    m = nm;
  }
  if (lane == 0) {
    float y = s + out_b[tgt];
    float lse = m + logf(ssum);
    float valid = (targets_len[b] > i + 1) ? 1.f : 0.f;
    term[row] = valid * (y - lse);
  }
}

__global__ void final_sum(const float* __restrict__ term, float* __restrict__ out) {
  __shared__ float red[256];
  float s = 0.f;
  for (int r = threadIdx.x; r < 2016; r += 256) s += term[r];
  red[threadIdx.x] = s;
  __syncthreads();
  for (int st = 128; st; st >>= 1) {
    if ((int)threadIdx.x < st) red[threadIdx.x] += red[threadIdx.x + st];
    __syncthreads();
  }
  if (threadIdx.x == 0) out[0] = -red[0];
}

// ---------------------------------------------------------------------------
extern "C" void kernel_launch(void* const* d_in, const int* in_sizes, int n_in,
                              void* d_out, int out_size, void* d_ws, size_t ws_size,
                              hipStream_t stream) {
  const int*   targets     = (const int*)d_in[0];
  const int*   targets_kws = (const int*)d_in[1];
  const float* sent_state  = (const float*)d_in[2];
  const int*   targets_len = (const int*)d_in[3];
  const float* emb_W       = (const float*)d_in[4];
  const float* w_Wih       = (const float*)d_in[5];
  const float* w_Whh       = (const float*)d_in[6];
  const float* w_bih       = (const float*)d_in[7];
  const float* w_bhh       = (const float*)d_in[8];
  const float* s_Wih       = (const float*)d_in[9];
  const float* s_Whh       = (const float*)d_in[10];
  const float* s_bih       = (const float*)d_in[11];
  const float* s_bhh       = (const float*)d_in[12];
  const float* out_W       = (const float*)d_in[13];
  const float* out_b       = (const float*)d_in[14];

  char* base = (char*)d_ws;
  size_t off = 0;
  auto alloc = [&](size_t bytes) -> void* {
    void* r = base + off;
    off += (bytes + 255) & ~(size_t)255;
    return r;
  };
  unsigned short* outWb   = (unsigned short*)alloc(32000ull * 1024 * 2);
  unsigned short* WihB    = (unsigned short*)alloc(3072ull * 1024 * 2);
  unsigned short* WhhB    = (unsigned short*)alloc(3072ull * 1024 * 2);
  unsigned short* sWihB   = (unsigned short*)alloc(3072ull * 1024 * 2);
  unsigned short* sWhhB   = (unsigned short*)alloc(3072ull * 1024 * 2);
  unsigned short* Xb      = (unsigned short*)alloc(2048ull * 1024 * 2);
  float*          Gi      = (float*)alloc(2048ull * 3072 * 4);
  unsigned short* WH      = (unsigned short*)alloc(2048ull * 1024 * 2);
  unsigned short* h_bf    = (unsigned short*)alloc(2 * 32ull * 1024 * 2);
  unsigned short* sent_bf = (unsigned short*)alloc(2 * 32ull * 1024 * 2);
  float2*         parts   = (float2*)alloc(2048ull * 250 * 8);
  float*          term    = (float*)alloc(2048ull * 4);
  unsigned*       flags   = (unsigned*)alloc(8192 * 4);   // [0..2047] recur, [2048..8191] gemm cvt
  unsigned*       gflags  = flags + 2048;

  zero_flags<<<32, 256, 0, stream>>>(flags, 8192);
  cvt4<<<3072, 256, 0, stream>>>(w_Wih, WihB, 786432);
  cvt4<<<3072, 256, 0, stream>>>(w_Whh, WhhB, 786432);
  cvt4<<<3072, 256, 0, stream>>>(s_Wih, sWihB, 786432);
  cvt4<<<3072, 256, 0, stream>>>(s_Whh, sWhhB, 786432);
  gatherx<<<2016, 256, 0, stream>>>(emb_W, targets, targets_kws, Xb);
  gemm_bt0<<<dim3(16, 24), 256, 0, stream>>>(Xb, WihB, Gi, 3072);

  fused_kernel<<<dim3(256), dim3(256), 0, stream>>>(
      Gi, WhhB, sWihB, sWhhB, h_bf, sent_bf, WH,
      w_bih, w_bhh, s_bih, s_bhh, targets, sent_state,
      flags, gflags, out_W, outWb, (float*)parts, out_b);

  row_loss<<<504, 256, 0, stream>>>(WH, outWb, out_b, targets, targets_len, parts, term);
  final_sum<<<1, 256, 0, stream>>>(term, (float*)d_out);
}

// Round 6
// 878.421 us; speedup vs baseline: 1.2222x; 1.2222x over previous
//
#include <hip/hip_runtime.h>

typedef __attribute__((ext_vector_type(8))) short short8;
typedef __attribute__((ext_vector_type(4))) float float4v;
typedef __attribute__((ext_vector_type(4))) unsigned short ushort4v;

#define DEV __device__ __forceinline__
#define AGENT __HIP_MEMORY_SCOPE_AGENT

DEV unsigned short f2bf(float f) {
  union { float f; unsigned u; } v; v.f = f;
  unsigned r = v.u + 0x7fffu + ((v.u >> 16) & 1u);
  return (unsigned short)(r >> 16);
}
DEV float bf2f(unsigned short h) {
  union { unsigned u; float f; } v; v.u = ((unsigned)h) << 16;
  return v.f;
}

// async global->LDS, 16B per lane; LDS dest is wave-uniform base + lane*16
DEV void gl2lds16(const void* g, void* l) {
  __builtin_amdgcn_global_load_lds(
      (const __attribute__((address_space(1))) void*)g,
      (__attribute__((address_space(3))) void*)l, 16, 0, 0);
}

// --- cross-workgroup data movement: LLC write-through / bypass ------------
DEV void ast32(unsigned short* p, unsigned v) {
  __hip_atomic_store((unsigned*)p, v, __ATOMIC_RELAXED, AGENT);
}
DEV short8 ald16(const unsigned short* p) {
  unsigned long long lo = __hip_atomic_load((const unsigned long long*)p,     __ATOMIC_RELAXED, AGENT);
  unsigned long long hi = __hip_atomic_load((const unsigned long long*)p + 1, __ATOMIC_RELAXED, AGENT);
  union { unsigned long long q[2]; short8 s; } u;
  u.q[0] = lo; u.q[1] = hi;
  return u.s;
}

// Grid barrier without RMW: wg stores flags[wg]=epoch (own cacheline);
// wave0's 64 lanes each poll one wg's flag, __all across the wave.
// __syncthreads before = vmcnt(0) drain (stores are write-through, at LLC).
DEV void bar(unsigned* flags, unsigned epoch) {
  __syncthreads();
  if (threadIdx.x < 64) {
    const int lane = threadIdx.x;
    if (lane == 0)
      __hip_atomic_store(&flags[blockIdx.x * 32], epoch, __ATOMIC_RELAXED, AGENT);
    bool ok = false;
    do {
      ok = ok || (__hip_atomic_load(&flags[lane * 32], __ATOMIC_RELAXED, AGENT) >= epoch);
    } while (!__all(ok));
  }
  __syncthreads();
}

__global__ __launch_bounds__(256) void zero_flags(unsigned* p, int n) {
  int i = blockIdx.x * 256 + threadIdx.x;
  if (i < n) p[i] = 0;
}

// ---------------------------------------------------------------------------
// fp32 -> bf16 convert, 4 elems/thread
__global__ __launch_bounds__(256) void cvt4(const float* __restrict__ in,
                                            unsigned short* __restrict__ out, int n4) {
  const int idx = blockIdx.x * 256 + threadIdx.x;
  if (idx >= n4) return;
  float4 v = ((const float4*)in)[idx];
  ushort4v o = { f2bf(v.x), f2bf(v.y), f2bf(v.z), f2bf(v.w) };
  ((ushort4v*)out)[idx] = o;
}

// ---------------------------------------------------------------------------
// Gather X[row] = [emb(kw_{i+1}) | emb(lw_i)] as bf16, row = i*32+b
__global__ __launch_bounds__(256) void gatherx(const float* __restrict__ emb,
                                               const int* __restrict__ targets,
                                               const int* __restrict__ tkws,
                                               unsigned short* __restrict__ X) {
  const int row = blockIdx.x;
  const int i = row >> 5, b = row & 31;
  const int t = threadIdx.x;
  const int kw = tkws[b * 64 + i + 1];
  const int lw = targets[b * 64 + i];
  const float4* src = (t < 128) ? (const float4*)(emb + (size_t)kw * 512)
                                : (const float4*)(emb + (size_t)lw * 512);
  const int c = t & 127;
  float4 v = src[c];
  ushort4v o = { f2bf(v.x), f2bf(v.y), f2bf(v.z), f2bf(v.w) };
  ((ushort4v*)(X + (size_t)row * 1024))[(t < 128 ? 0 : 128) + c] = o;
}

// ---------------------------------------------------------------------------
// C = A[M,1024] * B[N,1024]^T, 128x128 tile, BK=32, bf16 MFMA 16x16x32.
// fp32 C store (used for the Gi pre-GEMM only).
__global__ __launch_bounds__(256, 1) void gemm_bt0(
    const unsigned short* __restrict__ A,
    const unsigned short* __restrict__ B,
    float* __restrict__ out,
    int ldc) {
  __shared__ __align__(16) unsigned short As[128 * 32];
  __shared__ __align__(16) unsigned short Bs[128 * 32];
  const int tid = threadIdx.x;
  const int w = tid >> 6, lane = tid & 63;
  const int r4 = lane >> 2, c4 = lane & 3;
  const int m0 = blockIdx.x * 128, n0 = blockIdx.y * 128;
  const int m_off = (w & 1) * 64, n_off = (w >> 1) * 64;
  const int lrow = lane & 15, lk = (lane >> 4) * 8;

  const unsigned short* Ab = A + (size_t)(m0 + w * 16 + r4) * 1024 + c4 * 8;
  const unsigned short* Bb = B + (size_t)(n0 + w * 16 + r4) * 1024 + c4 * 8;

  float4v acc[4][4] = {};

  for (int k0 = 0; k0 < 1024; k0 += 32) {
    gl2lds16(Ab + k0,             &As[w * 512]);
    gl2lds16(Ab + 64 * 1024 + k0, &As[2048 + w * 512]);
    gl2lds16(Bb + k0,             &Bs[w * 512]);
    gl2lds16(Bb + 64 * 1024 + k0, &Bs[2048 + w * 512]);
    __syncthreads();
    short8 af[4], bfr[4];
#pragma unroll
    for (int t = 0; t < 4; t++) {
      af[t]  = *(const short8*)&As[(m_off + t * 16 + lrow) * 32 + lk];
      bfr[t] = *(const short8*)&Bs[(n_off + t * 16 + lrow) * 32 + lk];
    }
#pragma unroll
    for (int mt = 0; mt < 4; mt++)
#pragma unroll
      for (int nt = 0; nt < 4; nt++)
        acc[mt][nt] = __builtin_amdgcn_mfma_f32_16x16x32_bf16(af[mt], bfr[nt], acc[mt][nt], 0, 0, 0);
    __syncthreads();
  }

#pragma unroll
  for (int mt = 0; mt < 4; mt++) {
    const int gr = m0 + m_off + mt * 16 + (lane >> 4) * 4;
#pragma unroll
    for (int nt = 0; nt < 4; nt++) {
      const int gc = n0 + n_off + nt * 16 + lrow;
#pragma unroll
      for (int rg = 0; rg < 4; rg++)
        out[(size_t)(gr + rg) * ldc + gc] = acc[mt][nt][rg];
    }
  }
}

// ---------------------------------------------------------------------------
// Fused kernel, NORMAL launch, grid 256 x 256thr. 117KB static LDS forces
// 1 wg/CU; grid == #CUs, so all wgs are co-resident without the cooperative
// API.
//   wgs 0..63   : recurrence (identical to the R2-passing structure).
//   wgs 64..255 : (a) out_W fp32->bf16 (agent-scope write-through),
//                 (b) 192-wg flag barrier, (c) logits GEMM M=2048 N=32000,
//                 each 128-row M-tile gated on the recur epoch flags.
// Visibility model (R6): cross-wg data (WH/outWb) is WRITTEN only via
// agent-scope atomic stores (write-through to LLC, proven by R5); readers
// use ordinary cached loads (global_load_lds). Safe because each dispatch's
// acquire invalidates per-XCD L2, and no wg plain-reads a line before its
// flag gate, so every L2 first-touch fetches final data from LLC. This
// restores the standalone GEMM's ~21us/tile (R5's atomic-load staging was
// ~38us/tile: LLC latency, no TLP at 1 wave/SIMD, no L2 reuse).
__global__ __launch_bounds__(256, 1) void fused_kernel(
    const float* __restrict__ Gi,
    const unsigned short* __restrict__ WhhB,
    const unsigned short* __restrict__ sWihB,
    const unsigned short* __restrict__ sWhhB,
    unsigned short* __restrict__ h_bf,      // 2 x 32768 u16
    unsigned short* __restrict__ sent_bf,   // 2 x 32768 u16
    unsigned short* __restrict__ WH,
    const float* __restrict__ w_bih, const float* __restrict__ w_bhh,
    const float* __restrict__ s_bih, const float* __restrict__ s_bhh,
    const int* __restrict__ targets,
    const float* __restrict__ sent_state,
    unsigned* __restrict__ flags,           // [64*32] recur epochs
    unsigned* __restrict__ gflags,          // [192*32] cvt barrier
    const float* __restrict__ outW,
    unsigned short* __restrict__ outWb,
    float* __restrict__ parts,              // float2 [2048][250]
    const float* __restrict__ out_b) {
  __shared__ __align__(16) unsigned char smem[117248];
  const int tid = threadIdx.x;
  const int lane = tid & 63, wv = tid >> 6;

  // per-wave "any EOS at step i" bitmask (grid-uniform, both sides need it)
  unsigned long long eosmask;
  {
    bool e = false;
    if (lane < 63)
      for (int b = 0; b < 32; b++) e |= (targets[b * 64 + lane + 1] == 1);
    eosmask = __ballot(e);
  }

  if (blockIdx.x >= 64) {
    // ==================== GEMM side (192 wgs) ====================
    const int wg = blockIdx.x - 64;
    unsigned short* As = (unsigned short*)smem;            //  8 KB
    unsigned short* Bs = (unsigned short*)(smem + 8192);   //  8 KB
    float*          msb = (float*)(smem + 16384);          //  2 KB [2][128][2]

    // (a) out_W -> bf16, write-through so other XCDs see it
    for (int idx = wg * 256 + tid; idx < 8192000; idx += 192 * 256) {
      float4 v = ((const float4*)outW)[idx];
      unsigned p0 = (unsigned)f2bf(v.x) | ((unsigned)f2bf(v.y) << 16);
      unsigned p1 = (unsigned)f2bf(v.z) | ((unsigned)f2bf(v.w) << 16);
      unsigned long long pq = (unsigned long long)p0 | ((unsigned long long)p1 << 32);
      __hip_atomic_store((unsigned long long*)&outWb[(size_t)idx * 4], pq,
                         __ATOMIC_RELAXED, AGENT);
    }
    // (b) one-shot barrier among the 192 GEMM wgs
    __syncthreads();                       // drains the write-through stores
    if (tid == 0)
      __hip_atomic_store(&gflags[wg * 32], 1u, __ATOMIC_RELAXED, AGENT);
    if (tid < 64) {
      bool o0 = false, o1 = false, o2 = false;
      while (true) {
        o0 = o0 || (__hip_atomic_load(&gflags[tid * 32],         __ATOMIC_RELAXED, AGENT) != 0u);
        o1 = o1 || (__hip_atomic_load(&gflags[(64 + tid) * 32],  __ATOMIC_RELAXED, AGENT) != 0u);
        o2 = o2 || (__hip_atomic_load(&gflags[(128 + tid) * 32], __ATOMIC_RELAXED, AGENT) != 0u);
        if (__all(o0 && o1 && o2)) break;
        __builtin_amdgcn_s_sleep(32);
      }
    }
    __syncthreads();

    // (c) logits GEMM, 4000 blocks grid-strided m-major (mt nondecreasing
    // per wg => gates hit in increasing-epoch order, usually pre-passed)
    const int w = wv;
    const int r4 = lane >> 2, c4 = lane & 3;
    const int lrow = lane & 15, lk = (lane >> 4) * 8;
    const int m_off = (w & 1) * 64, n_off = (w >> 1) * 64;
    int gated_mt = -1;
    for (int bi = wg; bi < 4000; bi += 192) {
      const int mt = bi / 250, nt = bi - mt * 250;
      if (mt > gated_mt) {
        const int L = (4 * mt + 3 > 62) ? 62 : (4 * mt + 3);
        const unsigned E = 2u + (unsigned)L +
            (unsigned)__popcll(eosmask & ((1ull << L) - 1ull));
        if (tid < 64) {
          bool ok = false;
          while (true) {
            ok = ok || (__hip_atomic_load(&flags[tid * 32], __ATOMIC_RELAXED, AGENT) >= E);
            if (__all(ok)) break;
            __builtin_amdgcn_s_sleep(32);
          }
        }
        __syncthreads();
        gated_mt = mt;
      }
      const int m0 = mt * 128, n0 = nt * 128;
      const unsigned short* Ab = WH    + (size_t)(m0 + w * 16 + r4) * 1024 + c4 * 8;
      const unsigned short* Bb = outWb + (size_t)(n0 + w * 16 + r4) * 1024 + c4 * 8;
      float4v acc[4][4] = {};
      for (int k0 = 0; k0 < 1024; k0 += 32) {
        // cached async staging (post-gate => lines are final at LLC)
        gl2lds16(Ab + k0,             &As[w * 512]);
        gl2lds16(Ab + 64 * 1024 + k0, &As[2048 + w * 512]);
        gl2lds16(Bb + k0,             &Bs[w * 512]);
        gl2lds16(Bb + 64 * 1024 + k0, &Bs[2048 + w * 512]);
        __syncthreads();
        short8 af[4], bfr[4];
#pragma unroll
        for (int t = 0; t < 4; t++) {
          af[t]  = *(const short8*)&As[(m_off + t * 16 + lrow) * 32 + lk];
          bfr[t] = *(const short8*)&Bs[(n_off + t * 16 + lrow) * 32 + lk];
        }
#pragma unroll
        for (int a = 0; a < 4; a++)
#pragma unroll
          for (int b = 0; b < 4; b++)
            acc[a][b] = __builtin_amdgcn_mfma_f32_16x16x32_bf16(af[a], bfr[b], acc[a][b], 0, 0, 0);
        __syncthreads();
      }
      // epilogue: bias + per-row (max, sum-exp) over this 128-col tile
      float b4[4];
#pragma unroll
      for (int b = 0; b < 4; b++) b4[b] = out_b[n0 + n_off + b * 16 + lrow];
#pragma unroll
      for (int a = 0; a < 4; a++) {
#pragma unroll
        for (int rg = 0; rg < 4; rg++) {
          float v0 = acc[a][0][rg] + b4[0];
          float v1 = acc[a][1][rg] + b4[1];
          float v2 = acc[a][2][rg] + b4[2];
          float v3 = acc[a][3][rg] + b4[3];
          float mx = fmaxf(fmaxf(v0, v1), fmaxf(v2, v3));
#pragma unroll
          for (int d = 1; d < 16; d <<= 1) mx = fmaxf(mx, __shfl_xor(mx, d, 64));
          float s = __expf(v0 - mx) + __expf(v1 - mx) + __expf(v2 - mx) + __expf(v3 - mx);
#pragma unroll
          for (int d = 1; d < 16; d <<= 1) s += __shfl_xor(s, d, 64);
          if ((lane & 15) == 0) {
            int r = m_off + a * 16 + (lane >> 4) * 4 + rg;
            msb[(w >> 1) * 256 + r * 2 + 0] = mx;
            msb[(w >> 1) * 256 + r * 2 + 1] = s;
          }
        }
      }
      __syncthreads();
      if (tid < 128) {
        float m1 = msb[tid * 2], s1 = msb[tid * 2 + 1];
        float m2 = msb[256 + tid * 2], s2 = msb[256 + tid * 2 + 1];
        float M = fmaxf(m1, m2);
        float S = s1 * __expf(m1 - M) + s2 * __expf(m2 - M);
        ((float2*)parts)[(size_t)(m0 + tid) * 250 + nt] = make_float2(M, S);
      }
      __syncthreads();
    }
    return;
  }

  // ==================== recur side (64 wgs) ====================
  unsigned short* WhhS = (unsigned short*)smem;                  // 96 KB
  float (*Cred)[32][49] = (float (*)[32][49])(smem + 98304);     // 12544 B
  float (*hsl)[16] = (float (*)[16])(smem + 110848);             // 2 KB
  float (*ssl)[16] = (float (*)[16])(smem + 112896);             // 2 KB
  float (*whsl)[16] = (float (*)[16])(smem + 114944);            // 2 KB

  const int khalf = wv >> 1, mtile = wv & 1;
  const int jb = blockIdx.x * 16;
  const int lr = lane & 15;
  const int bb = mtile * 16 + lr;
  const int kb = khalf * 512 + (lane >> 4) * 8;
  const int cb = kb >> 3;          // 16B-chunk base within row
  const int swz = lr & 7;
  const int b0 = (tid * 2) >> 4, j0 = (tid * 2) & 15;
  unsigned epoch = 0;
  int scur = 0;

  // ---- one-time: Whh wg-slice -> LDS, XOR-swizzled 16B chunks ----
  for (int idx = tid; idx < 6144; idx += 256) {
    const int R = idx >> 7, c = idx & 127;     // R = g*16+rr, c = chunk
    const int g = R >> 4, rr = R & 15;
    short8 v = *(const short8*)&WhhB[((size_t)(g * 1024 + jb + rr)) * 1024 + c * 8];
    *(short8*)&WhhS[(R * 128 + (c ^ (rr & 7))) * 8] = v;
  }

  // ---- one-time: biases for this thread's 2 elements ----
  float bi[2][3], bh[2][3];
#pragma unroll
  for (int u = 0; u < 2; u++)
#pragma unroll
    for (int g = 0; g < 3; g++) {
      bi[u][g] = w_bih[g * 1024 + jb + j0 + u];
      bh[u][g] = w_bhh[g * 1024 + jb + j0 + u];
    }

  // ---- init state, publish to buffer 0 ----
  {
    float v0 = sent_state[b0 * 1024 + jb + j0];
    float v1 = sent_state[b0 * 1024 + jb + j0 + 1];
    hsl[b0][j0] = v0; hsl[b0][j0 + 1] = v1;
    ssl[b0][j0] = v0; ssl[b0][j0 + 1] = v1;
    unsigned pv = (unsigned)f2bf(v0) | ((unsigned)f2bf(v1) << 16);
    ast32(&h_bf[b0 * 1024 + jb + j0], pv);
    ast32(&sent_bf[b0 * 1024 + jb + j0], pv);
  }

  // ---- Gi prefetch for step 0 ----
  float2 gp[3];
  {
    const float* p = Gi + (size_t)b0 * 3072 + jb + j0;
    gp[0] = *(const float2*)(p);
    gp[1] = *(const float2*)(p + 1024);
    gp[2] = *(const float2*)(p + 2048);
  }

  epoch++; bar(flags, epoch);

  for (int i = 0; i < 63; i++) {
    const unsigned short* hr = h_bf + (i & 1) * 32768;
    unsigned short*       hw = h_bf + ((i + 1) & 1) * 32768;
    const bool anyeos = (eosmask >> i) & 1;

    // gh = h @ Whh^T  (A from LLC, B from LDS); batch-issue coherent loads
    short8 a[16];
#pragma unroll
    for (int ks = 0; ks < 16; ks++)
      a[ks] = ald16(&hr[bb * 1024 + kb + ks * 32]);
    float4v acc[3] = {};
#pragma unroll
    for (int ks = 0; ks < 16; ks++) {
#pragma unroll
      for (int g = 0; g < 3; g++) {
        short8 b8 = *(const short8*)&WhhS[((g * 16 + lr) * 128 + ((cb + ks * 4) ^ swz)) * 8];
        acc[g] = __builtin_amdgcn_mfma_f32_16x16x32_bf16(a[ks], b8, acc[g], 0, 0, 0);
      }
    }
#pragma unroll
    for (int g = 0; g < 3; g++)
#pragma unroll
      for (int rg = 0; rg < 4; rg++)
        Cred[khalf][mtile * 16 + (lane >> 4) * 4 + rg][g * 16 + lr] = acc[g][rg];
    __syncthreads();

    float wh2[2];
#pragma unroll
    for (int u = 0; u < 2; u++) {
      const int jj = j0 + u;
      float ghr = Cred[0][b0][jj]      + Cred[1][b0][jj]      + bh[u][0];
      float ghz = Cred[0][b0][16 + jj] + Cred[1][b0][16 + jj] + bh[u][1];
      float ghn = Cred[0][b0][32 + jj] + Cred[1][b0][32 + jj] + bh[u][2];
      float gir = ((float*)&gp[0])[u] + bi[u][0];
      float giz = ((float*)&gp[1])[u] + bi[u][1];
      float gin = ((float*)&gp[2])[u] + bi[u][2];
      float r = 1.f / (1.f + __expf(-(gir + ghr)));
      float z = 1.f / (1.f + __expf(-(giz + ghz)));
      float n = tanhf(gin + r * ghn);
      float wh = (1.f - z) * n + z * hsl[b0][jj];
      whsl[b0][jj] = wh;
      wh2[u] = wh;
    }
    {
      unsigned pv = (unsigned)f2bf(wh2[0]) | ((unsigned)f2bf(wh2[1]) << 16);
      ast32(&WH[(size_t)(i * 32 + b0) * 1024 + jb + j0], pv);
    }

    // Gi prefetch for next step (independent of barrier)
    if (i < 62) {
      const float* p = Gi + (size_t)((i + 1) * 32 + b0) * 3072 + jb + j0;
      gp[0] = *(const float2*)(p);
      gp[1] = *(const float2*)(p + 1024);
      gp[2] = *(const float2*)(p + 2048);
    }

    if (!anyeos) {
      hsl[b0][j0] = wh2[0]; hsl[b0][j0 + 1] = wh2[1];
      unsigned pv = (unsigned)f2bf(wh2[0]) | ((unsigned)f2bf(wh2[1]) << 16);
      ast32(&hw[b0 * 1024 + jb + j0], pv);
      epoch++; bar(flags, epoch);
    } else {
      epoch++; bar(flags, epoch);   // WH[i] visible grid-wide
      const unsigned short* sr = sent_bf + scur * 32768;
      unsigned short*       sw = sent_bf + (scur ^ 1) * 32768;
      // gi_s = wh @ sWih^T  (batch-issued coherent A-loads)
      short8 a2[16];
#pragma unroll
      for (int ks = 0; ks < 16; ks++)
        a2[ks] = ald16(&WH[(size_t)(i * 32 + bb) * 1024 + kb + ks * 32]);
      float4v acc2[3] = {};
#pragma unroll
      for (int ks = 0; ks < 16; ks++) {
#pragma unroll
        for (int g = 0; g < 3; g++) {
          short8 b8 = *(const short8*)&sWihB[(size_t)(g * 1024 + jb + lr) * 1024 + kb + ks * 32];
          acc2[g] = __builtin_amdgcn_mfma_f32_16x16x32_bf16(a2[ks], b8, acc2[g], 0, 0, 0);
        }
      }
#pragma unroll
      for (int g = 0; g < 3; g++)
#pragma unroll
        for (int rg = 0; rg < 4; rg++)
          Cred[khalf][mtile * 16 + (lane >> 4) * 4 + rg][g * 16 + lr] = acc2[g][rg];
      __syncthreads();
      float gis[2][3];
#pragma unroll
      for (int u = 0; u < 2; u++) {
        const int jj = j0 + u;
#pragma unroll
        for (int g = 0; g < 3; g++)
          gis[u][g] = Cred[0][b0][g * 16 + jj] + Cred[1][b0][g * 16 + jj] + s_bih[g * 1024 + jb + jj];
      }
      __syncthreads();
      // gh_s = sent @ sWhh^T  (batch-issued coherent A-loads)
      short8 a3[16];
#pragma unroll
      for (int ks = 0; ks < 16; ks++)
        a3[ks] = ald16(&sr[bb * 1024 + kb + ks * 32]);
      float4v acc3[3] = {};
#pragma unroll
      for (int ks = 0; ks < 16; ks++) {
#pragma unroll
        for (int g = 0; g < 3; g++) {
          short8 b8 = *(const short8*)&sWhhB[(size_t)(g * 1024 + jb + lr) * 1024 + kb + ks * 32];
          acc3[g] = __builtin_amdgcn_mfma_f32_16x16x32_bf16(a3[ks], b8, acc3[g], 0, 0, 0);
        }
      }
#pragma unroll
      for (int g = 0; g < 3; g++)
#pragma unroll
        for (int rg = 0; rg < 4; rg++)
          Cred[khalf][mtile * 16 + (lane >> 4) * 4 + rg][g * 16 + lr] = acc3[g][rg];
      __syncthreads();
      float ns2[2], nw2[2];
#pragma unroll
      for (int u = 0; u < 2; u++) {
        const int jj = j0 + u;
        float shr = Cred[0][b0][jj]      + Cred[1][b0][jj]      + s_bhh[jb + jj];
        float shz = Cred[0][b0][16 + jj] + Cred[1][b0][16 + jj] + s_bhh[1024 + jb + jj];
        float shn = Cred[0][b0][32 + jj] + Cred[1][b0][32 + jj] + s_bhh[2048 + jb + jj];
        float r = 1.f / (1.f + __expf(-(gis[u][0] + shr)));
        float z = 1.f / (1.f + __expf(-(gis[u][1] + shz)));
        float n = tanhf(gis[u][2] + r * shn);
        float s_old = ssl[b0][jj];
        float tmp = (1.f - z) * n + z * s_old;
        bool m = (targets[b0 * 64 + i + 1] == 1);
        ns2[u] = m ? tmp : s_old;
        nw2[u] = m ? tmp : whsl[b0][jj];
        ssl[b0][jj] = ns2[u];
        hsl[b0][jj] = nw2[u];
      }
      unsigned pvs = (unsigned)f2bf(ns2[0]) | ((unsigned)f2bf(ns2[1]) << 16);
      unsigned pvh = (unsigned)f2bf(nw2[0]) | ((unsigned)f2bf(nw2[1]) << 16);
      ast32(&sw[b0 * 1024 + jb + j0], pvs);
      ast32(&hw[b0 * 1024 + jb + j0], pvh);
      scur ^= 1;
      epoch++; bar(flags, epoch);
    }
  }
}

// ---------------------------------------------------------------------------
// Per row: y = WH[row].outW[tgt] + out_b[tgt]; lse from 250 (m,s) partials;
// term = valid * (y - lse). One wave per row.
__global__ __launch_bounds__(256) void row_loss(
    const unsigned short* __restrict__ WH,
    const unsigned short* __restrict__ outWb,
    const float* __restrict__ out_b,
    const int* __restrict__ targets,
    const int* __restrict__ targets_len,
    const float2* __restrict__ partials,
    float* __restrict__ term) {
  const int wv = threadIdx.x >> 6, lane = threadIdx.x & 63;
  const int row = blockIdx.x * 4 + wv;
  const int b = row & 31, i = row >> 5;
  const int tgt = targets[b * 64 + i + 1];
  const short8* a8 = (const short8*)(WH + (size_t)row * 1024);
  const short8* w8 = (const short8*)(outWb + (size_t)tgt * 1024);
  float s = 0.f;
#pragma unroll
  for (int c = 0; c < 2; c++) {
    short8 av = a8[lane + 64 * c];
    short8 wv8 = w8[lane + 64 * c];
#pragma unroll
    for (int j = 0; j < 8; j++)
      s += bf2f((unsigned short)av[j]) * bf2f((unsigned short)wv8[j]);
  }
#pragma unroll
  for (int d = 32; d; d >>= 1) s += __shfl_xor(s, d, 64);

  float m = -1e30f, ssum = 0.f;
  for (int vt = lane; vt < 250; vt += 64) {
    float2 pp = partials[(size_t)row * 250 + vt];
    float nm = fmaxf(m, pp.x);
    ssum = ssum * __expf(m - nm) + pp.y * __expf(pp.x - nm);
    m = nm;
  }
#pragma unroll
  for (int d = 32; d; d >>= 1) {
    float om = __shfl_xor(m, d, 64);
    float os = __shfl_xor(ssum, d, 64);
    float nm = fmaxf(m, om);
    ssum = ssum * __expf(m - nm) + os * __expf(om - nm);
    m = nm;
  }
  if (lane == 0) {
    float y = s + out_b[tgt];
    float lse = m + logf(ssum);
    float valid = (targets_len[b] > i + 1) ? 1.f : 0.f;
    term[row] = valid * (y - lse);
  }
}

__global__ void final_sum(const float* __restrict__ term, float* __restrict__ out) {
  __shared__ float red[256];
  float s = 0.f;
  for (int r = threadIdx.x; r < 2016; r += 256) s += term[r];
  red[threadIdx.x] = s;
  __syncthreads();
  for (int st = 128; st; st >>= 1) {
    if ((int)threadIdx.x < st) red[threadIdx.x] += red[threadIdx.x + st];
    __syncthreads();
  }
  if (threadIdx.x == 0) out[0] = -red[0];
}

// ---------------------------------------------------------------------------
extern "C" void kernel_launch(void* const* d_in, const int* in_sizes, int n_in,
                              void* d_out, int out_size, void* d_ws, size_t ws_size,
                              hipStream_t stream) {
  const int*   targets     = (const int*)d_in[0];
  const int*   targets_kws = (const int*)d_in[1];
  const float* sent_state  = (const float*)d_in[2];
  const int*   targets_len = (const int*)d_in[3];
  const float* emb_W       = (const float*)d_in[4];
  const float* w_Wih       = (const float*)d_in[5];
  const float* w_Whh       = (const float*)d_in[6];
  const float* w_bih       = (const float*)d_in[7];
  const float* w_bhh       = (const float*)d_in[8];
  const float* s_Wih       = (const float*)d_in[9];
  const float* s_Whh       = (const float*)d_in[10];
  const float* s_bih       = (const float*)d_in[11];
  const float* s_bhh       = (const float*)d_in[12];
  const float* out_W       = (const float*)d_in[13];
  const float* out_b       = (const float*)d_in[14];

  char* base = (char*)d_ws;
  size_t off = 0;
  auto alloc = [&](size_t bytes) -> void* {
    void* r = base + off;
    off += (bytes + 255) & ~(size_t)255;
    return r;
  };
  unsigned short* outWb   = (unsigned short*)alloc(32000ull * 1024 * 2);
  unsigned short* WihB    = (unsigned short*)alloc(3072ull * 1024 * 2);
  unsigned short* WhhB    = (unsigned short*)alloc(3072ull * 1024 * 2);
  unsigned short* sWihB   = (unsigned short*)alloc(3072ull * 1024 * 2);
  unsigned short* sWhhB   = (unsigned short*)alloc(3072ull * 1024 * 2);
  unsigned short* Xb      = (unsigned short*)alloc(2048ull * 1024 * 2);
  float*          Gi      = (float*)alloc(2048ull * 3072 * 4);
  unsigned short* WH      = (unsigned short*)alloc(2048ull * 1024 * 2);
  unsigned short* h_bf    = (unsigned short*)alloc(2 * 32ull * 1024 * 2);
  unsigned short* sent_bf = (unsigned short*)alloc(2 * 32ull * 1024 * 2);
  float2*         parts   = (float2*)alloc(2048ull * 250 * 8);
  float*          term    = (float*)alloc(2048ull * 4);
  unsigned*       flags   = (unsigned*)alloc(8192 * 4);   // [0..2047] recur, [2048..8191] gemm cvt
  unsigned*       gflags  = flags + 2048;

  zero_flags<<<32, 256, 0, stream>>>(flags, 8192);
  cvt4<<<3072, 256, 0, stream>>>(w_Wih, WihB, 786432);
  cvt4<<<3072, 256, 0, stream>>>(w_Whh, WhhB, 786432);
  cvt4<<<3072, 256, 0, stream>>>(s_Wih, sWihB, 786432);
  cvt4<<<3072, 256, 0, stream>>>(s_Whh, sWhhB, 786432);
  gatherx<<<2016, 256, 0, stream>>>(emb_W, targets, targets_kws, Xb);
  gemm_bt0<<<dim3(16, 24), 256, 0, stream>>>(Xb, WihB, Gi, 3072);

  fused_kernel<<<dim3(256), dim3(256), 0, stream>>>(
      Gi, WhhB, sWihB, sWhhB, h_bf, sent_bf, WH,
      w_bih, w_bhh, s_bih, s_bhh, targets, sent_state,
      flags, gflags, out_W, outWb, (float*)parts, out_b);

  row_loss<<<504, 256, 0, stream>>>(WH, outWb, out_b, targets, targets_len, parts, term);
  final_sum<<<1, 256, 0, stream>>>(term, (float*)d_out);
}

// Round 7
// 772.411 us; speedup vs baseline: 1.3899x; 1.1372x over previous
//
#include <hip/hip_runtime.h>

typedef __attribute__((ext_vector_type(8))) short short8;
typedef __attribute__((ext_vector_type(4))) float float4v;
typedef __attribute__((ext_vector_type(4))) unsigned short ushort4v;

#define DEV __device__ __forceinline__
#define AGENT __HIP_MEMORY_SCOPE_AGENT

DEV unsigned short f2bf(float f) {
  union { float f; unsigned u; } v; v.f = f;
  unsigned r = v.u + 0x7fffu + ((v.u >> 16) & 1u);
  return (unsigned short)(r >> 16);
}
DEV float bf2f(unsigned short h) {
  union { unsigned u; float f; } v; v.u = ((unsigned)h) << 16;
  return v.f;
}

// async global->LDS, 16B per lane; LDS dest is wave-uniform base + lane*16
DEV void gl2lds16(const void* g, void* l) {
  __builtin_amdgcn_global_load_lds(
      (const __attribute__((address_space(1))) void*)g,
      (__attribute__((address_space(3))) void*)l, 16, 0, 0);
}

// --- cross-workgroup data movement: LLC write-through / bypass ------------
DEV void ast32(unsigned short* p, unsigned v) {
  __hip_atomic_store((unsigned*)p, v, __ATOMIC_RELAXED, AGENT);
}
DEV short8 ald16(const unsigned short* p) {
  unsigned long long lo = __hip_atomic_load((const unsigned long long*)p,     __ATOMIC_RELAXED, AGENT);
  unsigned long long hi = __hip_atomic_load((const unsigned long long*)p + 1, __ATOMIC_RELAXED, AGENT);
  union { unsigned long long q[2]; short8 s; } u;
  u.q[0] = lo; u.q[1] = hi;
  return u.s;
}

// Grid barrier without RMW: wg stores flags[wg]=epoch (own cacheline);
// wave0's 64 lanes each poll one wg's flag, __all across the wave.
DEV void bar(unsigned* flags, unsigned epoch) {
  __syncthreads();
  if (threadIdx.x < 64) {
    const int lane = threadIdx.x;
    if (lane == 0)
      __hip_atomic_store(&flags[blockIdx.x * 32], epoch, __ATOMIC_RELAXED, AGENT);
    bool ok = false;
    do {
      ok = ok || (__hip_atomic_load(&flags[lane * 32], __ATOMIC_RELAXED, AGENT) >= epoch);
    } while (!__all(ok));
  }
  __syncthreads();
}

__global__ __launch_bounds__(256) void zero_flags(unsigned* p, int n) {
  int i = blockIdx.x * 256 + threadIdx.x;
  if (i < n) p[i] = 0;
}

// ---------------------------------------------------------------------------
// fp32 -> bf16 convert, 4 elems/thread
__global__ __launch_bounds__(256) void cvt4(const float* __restrict__ in,
                                            unsigned short* __restrict__ out, int n4) {
  const int idx = blockIdx.x * 256 + threadIdx.x;
  if (idx >= n4) return;
  float4 v = ((const float4*)in)[idx];
  ushort4v o = { f2bf(v.x), f2bf(v.y), f2bf(v.z), f2bf(v.w) };
  ((ushort4v*)out)[idx] = o;
}

// ---------------------------------------------------------------------------
// Gather X[row] = [emb(kw_{i+1}) | emb(lw_i)] as bf16, row = i*32+b
__global__ __launch_bounds__(256) void gatherx(const float* __restrict__ emb,
                                               const int* __restrict__ targets,
                                               const int* __restrict__ tkws,
                                               unsigned short* __restrict__ X) {
  const int row = blockIdx.x;
  const int i = row >> 5, b = row & 31;
  const int t = threadIdx.x;
  const int kw = tkws[b * 64 + i + 1];
  const int lw = targets[b * 64 + i];
  const float4* src = (t < 128) ? (const float4*)(emb + (size_t)kw * 512)
                                : (const float4*)(emb + (size_t)lw * 512);
  const int c = t & 127;
  float4 v = src[c];
  ushort4v o = { f2bf(v.x), f2bf(v.y), f2bf(v.z), f2bf(v.w) };
  ((ushort4v*)(X + (size_t)row * 1024))[(t < 128 ? 0 : 128) + c] = o;
}

// ---------------------------------------------------------------------------
// C = A[M,1024] * B[N,1024]^T, 128x128 tile, BK=32, bf16 MFMA 16x16x32.
// fp32 C store (used for the Gi pre-GEMM only).
__global__ __launch_bounds__(256, 1) void gemm_bt0(
    const unsigned short* __restrict__ A,
    const unsigned short* __restrict__ B,
    float* __restrict__ out,
    int ldc) {
  __shared__ __align__(16) unsigned short As[128 * 32];
  __shared__ __align__(16) unsigned short Bs[128 * 32];
  const int tid = threadIdx.x;
  const int w = tid >> 6, lane = tid & 63;
  const int r4 = lane >> 2, c4 = lane & 3;
  const int m0 = blockIdx.x * 128, n0 = blockIdx.y * 128;
  const int m_off = (w & 1) * 64, n_off = (w >> 1) * 64;
  const int lrow = lane & 15, lk = (lane >> 4) * 8;

  const unsigned short* Ab = A + (size_t)(m0 + w * 16 + r4) * 1024 + c4 * 8;
  const unsigned short* Bb = B + (size_t)(n0 + w * 16 + r4) * 1024 + c4 * 8;

  float4v acc[4][4] = {};

  for (int k0 = 0; k0 < 1024; k0 += 32) {
    gl2lds16(Ab + k0,             &As[w * 512]);
    gl2lds16(Ab + 64 * 1024 + k0, &As[2048 + w * 512]);
    gl2lds16(Bb + k0,             &Bs[w * 512]);
    gl2lds16(Bb + 64 * 1024 + k0, &Bs[2048 + w * 512]);
    __syncthreads();
    short8 af[4], bfr[4];
#pragma unroll
    for (int t = 0; t < 4; t++) {
      af[t]  = *(const short8*)&As[(m_off + t * 16 + lrow) * 32 + lk];
      bfr[t] = *(const short8*)&Bs[(n_off + t * 16 + lrow) * 32 + lk];
    }
#pragma unroll
    for (int mt = 0; mt < 4; mt++)
#pragma unroll
      for (int nt = 0; nt < 4; nt++)
        acc[mt][nt] = __builtin_amdgcn_mfma_f32_16x16x32_bf16(af[mt], bfr[nt], acc[mt][nt], 0, 0, 0);
    __syncthreads();
  }

#pragma unroll
  for (int mt = 0; mt < 4; mt++) {
    const int gr = m0 + m_off + mt * 16 + (lane >> 4) * 4;
#pragma unroll
    for (int nt = 0; nt < 4; nt++) {
      const int gc = n0 + n_off + nt * 16 + lrow;
#pragma unroll
      for (int rg = 0; rg < 4; rg++)
        out[(size_t)(gr + rg) * ldc + gc] = acc[mt][nt][rg];
    }
  }
}

// ---------------------------------------------------------------------------
// Fused kernel, NORMAL launch, grid 256 x 256thr, 1 wg/CU (117KB LDS).
//   wgs 0..63   : recurrence (identical to the R6-passing structure).
//   wgs 64..255 : out_W cvt -> barrier -> logits GEMM, now 128x256 tiles
//                 (2000 tiles), BK=32, DOUBLE-BUFFERED LDS with next-K
//                 prefetch issued before compute (one barrier per K-step).
//                 R6 measured ~27us/tile with the 2-barrier 128x128 loop at
//                 1 wg/CU (latency-naked); this pipeline + bigger tile
//                 targets ~10us/tile -> GEMM side becomes gate-bound on the
//                 recurrence.
// Visibility model unchanged from R6 (proven): writers use agent-scope
// atomic stores (write-through), readers use cached loads only after the
// flag gate; per-XCD L2 starts invalidated at dispatch.
__global__ __launch_bounds__(256, 1) void fused_kernel(
    const float* __restrict__ Gi,
    const unsigned short* __restrict__ WhhB,
    const unsigned short* __restrict__ sWihB,
    const unsigned short* __restrict__ sWhhB,
    unsigned short* __restrict__ h_bf,      // 2 x 32768 u16
    unsigned short* __restrict__ sent_bf,   // 2 x 32768 u16
    unsigned short* __restrict__ WH,
    const float* __restrict__ w_bih, const float* __restrict__ w_bhh,
    const float* __restrict__ s_bih, const float* __restrict__ s_bhh,
    const int* __restrict__ targets,
    const float* __restrict__ sent_state,
    unsigned* __restrict__ flags,           // [64*32] recur epochs
    unsigned* __restrict__ gflags,          // [192*32] cvt barrier
    const float* __restrict__ outW,
    unsigned short* __restrict__ outWb,
    float* __restrict__ parts,              // float2 [2048][125]
    const float* __restrict__ out_b) {
  __shared__ __align__(16) unsigned char smem[117248];
  const int tid = threadIdx.x;
  const int lane = tid & 63, wv = tid >> 6;

  // per-wave "any EOS at step i" bitmask (grid-uniform, both sides need it)
  unsigned long long eosmask;
  {
    bool e = false;
    if (lane < 63)
      for (int b = 0; b < 32; b++) e |= (targets[b * 64 + lane + 1] == 1);
    eosmask = __ballot(e);
  }

  if (blockIdx.x >= 64) {
    // ==================== GEMM side (192 wgs) ====================
    const int wg = blockIdx.x - 64;
    unsigned short* As0 = (unsigned short*)smem;             // 2 x 8 KB
    unsigned short* Bs0 = (unsigned short*)(smem + 16384);   // 2 x 16 KB
    float*          msb = (float*)(smem + 49152);            // 2 KB [2][128][2]

    // (a) out_W -> bf16, write-through so other XCDs see it
    for (int idx = wg * 256 + tid; idx < 8192000; idx += 192 * 256) {
      float4 v = ((const float4*)outW)[idx];
      unsigned p0 = (unsigned)f2bf(v.x) | ((unsigned)f2bf(v.y) << 16);
      unsigned p1 = (unsigned)f2bf(v.z) | ((unsigned)f2bf(v.w) << 16);
      unsigned long long pq = (unsigned long long)p0 | ((unsigned long long)p1 << 32);
      __hip_atomic_store((unsigned long long*)&outWb[(size_t)idx * 4], pq,
                         __ATOMIC_RELAXED, AGENT);
    }
    // (b) one-shot barrier among the 192 GEMM wgs
    __syncthreads();                       // drains the write-through stores
    if (tid == 0)
      __hip_atomic_store(&gflags[wg * 32], 1u, __ATOMIC_RELAXED, AGENT);
    if (tid < 64) {
      bool o0 = false, o1 = false, o2 = false;
      while (true) {
        o0 = o0 || (__hip_atomic_load(&gflags[tid * 32],         __ATOMIC_RELAXED, AGENT) != 0u);
        o1 = o1 || (__hip_atomic_load(&gflags[(64 + tid) * 32],  __ATOMIC_RELAXED, AGENT) != 0u);
        o2 = o2 || (__hip_atomic_load(&gflags[(128 + tid) * 32], __ATOMIC_RELAXED, AGENT) != 0u);
        if (__all(o0 && o1 && o2)) break;
        __builtin_amdgcn_s_sleep(32);
      }
    }
    __syncthreads();

    // (c) logits GEMM, 2000 tiles (16 mt x 125 nt), m-major grid-stride
    const int w = wv;
    const int r4 = lane >> 2, c4 = lane & 3;
    const int lrow = lane & 15, lk = (lane >> 4) * 8;
    const int m_off = (w & 1) * 64, n_off = (w >> 1) * 128;
    int gated_mt = -1;
    for (int bi = wg; bi < 2000; bi += 192) {
      const int mt = bi / 125, nt = bi - mt * 125;
      if (mt > gated_mt) {
        const int L = (4 * mt + 3 > 62) ? 62 : (4 * mt + 3);
        const unsigned E = 2u + (unsigned)L +
            (unsigned)__popcll(eosmask & ((1ull << L) - 1ull));
        if (tid < 64) {
          bool ok = false;
          while (true) {
            ok = ok || (__hip_atomic_load(&flags[tid * 32], __ATOMIC_RELAXED, AGENT) >= E);
            if (__all(ok)) break;
            __builtin_amdgcn_s_sleep(32);
          }
        }
        __syncthreads();
        gated_mt = mt;
      }
      const int m0 = mt * 128, n0 = nt * 256;
      const unsigned short* Ab = WH    + (size_t)(m0 + w * 16 + r4) * 1024 + c4 * 8;
      const unsigned short* Bb = outWb + (size_t)(n0 + w * 16 + r4) * 1024 + c4 * 8;
      float4v acc[4][8] = {};

#define STAGE(buf, k0)                                                        \
      {                                                                       \
        unsigned short* A_ = As0 + (buf) * 4096;                              \
        unsigned short* B_ = Bs0 + (buf) * 8192;                              \
        gl2lds16(Ab + (k0),              A_ + (w * 16) * 32);                 \
        gl2lds16(Ab + 64 * 1024 + (k0),  A_ + (64 + w * 16) * 32);            \
        gl2lds16(Bb + (k0),              B_ + (w * 16) * 32);                 \
        gl2lds16(Bb + 64 * 1024 + (k0),  B_ + (64 + w * 16) * 32);            \
        gl2lds16(Bb + 128 * 1024 + (k0), B_ + (128 + w * 16) * 32);           \
        gl2lds16(Bb + 192 * 1024 + (k0), B_ + (192 + w * 16) * 32);           \
      }

      int cur = 0;
      STAGE(0, 0)
      __syncthreads();
      for (int t = 0; t < 32; ++t) {
        if (t < 31) STAGE(cur ^ 1, (t + 1) * 32)
        const unsigned short* A_ = As0 + cur * 4096;
        const unsigned short* B_ = Bs0 + cur * 8192;
        short8 af[4], bfr[8];
#pragma unroll
        for (int x = 0; x < 4; x++)
          af[x] = *(const short8*)&A_[(m_off + x * 16 + lrow) * 32 + lk];
#pragma unroll
        for (int y = 0; y < 8; y++)
          bfr[y] = *(const short8*)&B_[(n_off + y * 16 + lrow) * 32 + lk];
#pragma unroll
        for (int a = 0; a < 4; a++)
#pragma unroll
          for (int b = 0; b < 8; b++)
            acc[a][b] = __builtin_amdgcn_mfma_f32_16x16x32_bf16(af[a], bfr[b], acc[a][b], 0, 0, 0);
        __syncthreads();   // drains prefetch (vmcnt0) + protects buffer swap
        cur ^= 1;
      }
#undef STAGE

      // epilogue: bias + per-row (max, sum-exp) over this 256-col tile
      float b8v[8];
#pragma unroll
      for (int b = 0; b < 8; b++) b8v[b] = out_b[n0 + n_off + b * 16 + lrow];
#pragma unroll
      for (int a = 0; a < 4; a++) {
#pragma unroll
        for (int rg = 0; rg < 4; rg++) {
          float vv[8];
#pragma unroll
          for (int b = 0; b < 8; b++) vv[b] = acc[a][b][rg] + b8v[b];
          float mx = vv[0];
#pragma unroll
          for (int b = 1; b < 8; b++) mx = fmaxf(mx, vv[b]);
#pragma unroll
          for (int d = 1; d < 16; d <<= 1) mx = fmaxf(mx, __shfl_xor(mx, d, 64));
          float s = 0.f;
#pragma unroll
          for (int b = 0; b < 8; b++) s += __expf(vv[b] - mx);
#pragma unroll
          for (int d = 1; d < 16; d <<= 1) s += __shfl_xor(s, d, 64);
          if ((lane & 15) == 0) {
            int r = m_off + a * 16 + (lane >> 4) * 4 + rg;
            msb[(w >> 1) * 256 + r * 2 + 0] = mx;
            msb[(w >> 1) * 256 + r * 2 + 1] = s;
          }
        }
      }
      __syncthreads();
      if (tid < 128) {
        float m1 = msb[tid * 2], s1 = msb[tid * 2 + 1];
        float m2 = msb[256 + tid * 2], s2 = msb[256 + tid * 2 + 1];
        float M = fmaxf(m1, m2);
        float S = s1 * __expf(m1 - M) + s2 * __expf(m2 - M);
        ((float2*)parts)[(size_t)(m0 + tid) * 125 + nt] = make_float2(M, S);
      }
      __syncthreads();
    }
    return;
  }

  // ==================== recur side (64 wgs) ====================
  unsigned short* WhhS = (unsigned short*)smem;                  // 96 KB
  float (*Cred)[32][49] = (float (*)[32][49])(smem + 98304);     // 12544 B
  float (*hsl)[16] = (float (*)[16])(smem + 110848);             // 2 KB
  float (*ssl)[16] = (float (*)[16])(smem + 112896);             // 2 KB
  float (*whsl)[16] = (float (*)[16])(smem + 114944);            // 2 KB

  const int khalf = wv >> 1, mtile = wv & 1;
  const int jb = blockIdx.x * 16;
  const int lr = lane & 15;
  const int bb = mtile * 16 + lr;
  const int kb = khalf * 512 + (lane >> 4) * 8;
  const int cb = kb >> 3;          // 16B-chunk base within row
  const int swz = lr & 7;
  const int b0 = (tid * 2) >> 4, j0 = (tid * 2) & 15;
  unsigned epoch = 0;
  int scur = 0;

  // ---- one-time: Whh wg-slice -> LDS, XOR-swizzled 16B chunks ----
  for (int idx = tid; idx < 6144; idx += 256) {
    const int R = idx >> 7, c = idx & 127;     // R = g*16+rr, c = chunk
    const int g = R >> 4, rr = R & 15;
    short8 v = *(const short8*)&WhhB[((size_t)(g * 1024 + jb + rr)) * 1024 + c * 8];
    *(short8*)&WhhS[(R * 128 + (c ^ (rr & 7))) * 8] = v;
  }

  // ---- one-time: biases for this thread's 2 elements ----
  float bi[2][3], bh[2][3];
#pragma unroll
  for (int u = 0; u < 2; u++)
#pragma unroll
    for (int g = 0; g < 3; g++) {
      bi[u][g] = w_bih[g * 1024 + jb + j0 + u];
      bh[u][g] = w_bhh[g * 1024 + jb + j0 + u];
    }

  // ---- init state, publish to buffer 0 ----
  {
    float v0 = sent_state[b0 * 1024 + jb + j0];
    float v1 = sent_state[b0 * 1024 + jb + j0 + 1];
    hsl[b0][j0] = v0; hsl[b0][j0 + 1] = v1;
    ssl[b0][j0] = v0; ssl[b0][j0 + 1] = v1;
    unsigned pv = (unsigned)f2bf(v0) | ((unsigned)f2bf(v1) << 16);
    ast32(&h_bf[b0 * 1024 + jb + j0], pv);
    ast32(&sent_bf[b0 * 1024 + jb + j0], pv);
  }

  // ---- Gi prefetch for step 0 ----
  float2 gp[3];
  {
    const float* p = Gi + (size_t)b0 * 3072 + jb + j0;
    gp[0] = *(const float2*)(p);
    gp[1] = *(const float2*)(p + 1024);
    gp[2] = *(const float2*)(p + 2048);
  }

  epoch++; bar(flags, epoch);

  for (int i = 0; i < 63; i++) {
    const unsigned short* hr = h_bf + (i & 1) * 32768;
    unsigned short*       hw = h_bf + ((i + 1) & 1) * 32768;
    const bool anyeos = (eosmask >> i) & 1;

    // gh = h @ Whh^T  (A from LLC, B from LDS); batch-issue coherent loads
    short8 a[16];
#pragma unroll
    for (int ks = 0; ks < 16; ks++)
      a[ks] = ald16(&hr[bb * 1024 + kb + ks * 32]);
    float4v acc[3] = {};
#pragma unroll
    for (int ks = 0; ks < 16; ks++) {
#pragma unroll
      for (int g = 0; g < 3; g++) {
        short8 b8 = *(const short8*)&WhhS[((g * 16 + lr) * 128 + ((cb + ks * 4) ^ swz)) * 8];
        acc[g] = __builtin_amdgcn_mfma_f32_16x16x32_bf16(a[ks], b8, acc[g], 0, 0, 0);
      }
    }
#pragma unroll
    for (int g = 0; g < 3; g++)
#pragma unroll
      for (int rg = 0; rg < 4; rg++)
        Cred[khalf][mtile * 16 + (lane >> 4) * 4 + rg][g * 16 + lr] = acc[g][rg];
    __syncthreads();

    float wh2[2];
#pragma unroll
    for (int u = 0; u < 2; u++) {
      const int jj = j0 + u;
      float ghr = Cred[0][b0][jj]      + Cred[1][b0][jj]      + bh[u][0];
      float ghz = Cred[0][b0][16 + jj] + Cred[1][b0][16 + jj] + bh[u][1];
      float ghn = Cred[0][b0][32 + jj] + Cred[1][b0][32 + jj] + bh[u][2];
      float gir = ((float*)&gp[0])[u] + bi[u][0];
      float giz = ((float*)&gp[1])[u] + bi[u][1];
      float gin = ((float*)&gp[2])[u] + bi[u][2];
      float r = 1.f / (1.f + __expf(-(gir + ghr)));
      float z = 1.f / (1.f + __expf(-(giz + ghz)));
      float n = tanhf(gin + r * ghn);
      float wh = (1.f - z) * n + z * hsl[b0][jj];
      whsl[b0][jj] = wh;
      wh2[u] = wh;
    }
    {
      unsigned pv = (unsigned)f2bf(wh2[0]) | ((unsigned)f2bf(wh2[1]) << 16);
      ast32(&WH[(size_t)(i * 32 + b0) * 1024 + jb + j0], pv);
    }

    // Gi prefetch for next step (independent of barrier)
    if (i < 62) {
      const float* p = Gi + (size_t)((i + 1) * 32 + b0) * 3072 + jb + j0;
      gp[0] = *(const float2*)(p);
      gp[1] = *(const float2*)(p + 1024);
      gp[2] = *(const float2*)(p + 2048);
    }

    if (!anyeos) {
      hsl[b0][j0] = wh2[0]; hsl[b0][j0 + 1] = wh2[1];
      unsigned pv = (unsigned)f2bf(wh2[0]) | ((unsigned)f2bf(wh2[1]) << 16);
      ast32(&hw[b0 * 1024 + jb + j0], pv);
      epoch++; bar(flags, epoch);
    } else {
      epoch++; bar(flags, epoch);   // WH[i] visible grid-wide
      const unsigned short* sr = sent_bf + scur * 32768;
      unsigned short*       sw = sent_bf + (scur ^ 1) * 32768;
      // gi_s = wh @ sWih^T  (batch-issued coherent A-loads)
      short8 a2[16];
#pragma unroll
      for (int ks = 0; ks < 16; ks++)
        a2[ks] = ald16(&WH[(size_t)(i * 32 + bb) * 1024 + kb + ks * 32]);
      float4v acc2[3] = {};
#pragma unroll
      for (int ks = 0; ks < 16; ks++) {
#pragma unroll
        for (int g = 0; g < 3; g++) {
          short8 b8 = *(const short8*)&sWihB[(size_t)(g * 1024 + jb + lr) * 1024 + kb + ks * 32];
          acc2[g] = __builtin_amdgcn_mfma_f32_16x16x32_bf16(a2[ks], b8, acc2[g], 0, 0, 0);
        }
      }
#pragma unroll
      for (int g = 0; g < 3; g++)
#pragma unroll
        for (int rg = 0; rg < 4; rg++)
          Cred[khalf][mtile * 16 + (lane >> 4) * 4 + rg][g * 16 + lr] = acc2[g][rg];
      __syncthreads();
      float gis[2][3];
#pragma unroll
      for (int u = 0; u < 2; u++) {
        const int jj = j0 + u;
#pragma unroll
        for (int g = 0; g < 3; g++)
          gis[u][g] = Cred[0][b0][g * 16 + jj] + Cred[1][b0][g * 16 + jj] + s_bih[g * 1024 + jb + jj];
      }
      __syncthreads();
      // gh_s = sent @ sWhh^T  (batch-issued coherent A-loads)
      short8 a3[16];
#pragma unroll
      for (int ks = 0; ks < 16; ks++)
        a3[ks] = ald16(&sr[bb * 1024 + kb + ks * 32]);
      float4v acc3[3] = {};
#pragma unroll
      for (int ks = 0; ks < 16; ks++) {
#pragma unroll
        for (int g = 0; g < 3; g++) {
          short8 b8 = *(const short8*)&sWhhB[(size_t)(g * 1024 + jb + lr) * 1024 + kb + ks * 32];
          acc3[g] = __builtin_amdgcn_mfma_f32_16x16x32_bf16(a3[ks], b8, acc3[g], 0, 0, 0);
        }
      }
#pragma unroll
      for (int g = 0; g < 3; g++)
#pragma unroll
        for (int rg = 0; rg < 4; rg++)
          Cred[khalf][mtile * 16 + (lane >> 4) * 4 + rg][g * 16 + lr] = acc3[g][rg];
      __syncthreads();
      float ns2[2], nw2[2];
#pragma unroll
      for (int u = 0; u < 2; u++) {
        const int jj = j0 + u;
        float shr = Cred[0][b0][jj]      + Cred[1][b0][jj]      + s_bhh[jb + jj];
        float shz = Cred[0][b0][16 + jj] + Cred[1][b0][16 + jj] + s_bhh[1024 + jb + jj];
        float shn = Cred[0][b0][32 + jj] + Cred[1][b0][32 + jj] + s_bhh[2048 + jb + jj];
        float r = 1.f / (1.f + __expf(-(gis[u][0] + shr)));
        float z = 1.f / (1.f + __expf(-(gis[u][1] + shz)));
        float n = tanhf(gis[u][2] + r * shn);
        float s_old = ssl[b0][jj];
        float tmp = (1.f - z) * n + z * s_old;
        bool m = (targets[b0 * 64 + i + 1] == 1);
        ns2[u] = m ? tmp : s_old;
        nw2[u] = m ? tmp : whsl[b0][jj];
        ssl[b0][jj] = ns2[u];
        hsl[b0][jj] = nw2[u];
      }
      unsigned pvs = (unsigned)f2bf(ns2[0]) | ((unsigned)f2bf(ns2[1]) << 16);
      unsigned pvh = (unsigned)f2bf(nw2[0]) | ((unsigned)f2bf(nw2[1]) << 16);
      ast32(&sw[b0 * 1024 + jb + j0], pvs);
      ast32(&hw[b0 * 1024 + jb + j0], pvh);
      scur ^= 1;
      epoch++; bar(flags, epoch);
    }
  }
}

// ---------------------------------------------------------------------------
// Per row: y = WH[row].outW[tgt] + out_b[tgt]; lse from 125 (m,s) partials;
// term = valid * (y - lse). One wave per row.
__global__ __launch_bounds__(256) void row_loss(
    const unsigned short* __restrict__ WH,
    const unsigned short* __restrict__ outWb,
    const float* __restrict__ out_b,
    const int* __restrict__ targets,
    const int* __restrict__ targets_len,
    const float2* __restrict__ partials,
    float* __restrict__ term) {
  const int wv = threadIdx.x >> 6, lane = threadIdx.x & 63;
  const int row = blockIdx.x * 4 + wv;
  const int b = row & 31, i = row >> 5;
  const int tgt = targets[b * 64 + i + 1];
  const short8* a8 = (const short8*)(WH + (size_t)row * 1024);
  const short8* w8 = (const short8*)(outWb + (size_t)tgt * 1024);
  float s = 0.f;
#pragma unroll
  for (int c = 0; c < 2; c++) {
    short8 av = a8[lane + 64 * c];
    short8 wv8 = w8[lane + 64 * c];
#pragma unroll
    for (int j = 0; j < 8; j++)
      s += bf2f((unsigned short)av[j]) * bf2f((unsigned short)wv8[j]);
  }
#pragma unroll
  for (int d = 32; d; d >>= 1) s += __shfl_xor(s, d, 64);

  float m = -1e30f, ssum = 0.f;
  for (int vt = lane; vt < 125; vt += 64) {
    float2 pp = partials[(size_t)row * 125 + vt];
    float nm = fmaxf(m, pp.x);
    ssum = ssum * __expf(m - nm) + pp.y * __expf(pp.x - nm);
    m = nm;
  }
#pragma unroll
  for (int d = 32; d; d >>= 1) {
    float om = __shfl_xor(m, d, 64);
    float os = __shfl_xor(ssum, d, 64);
    float nm = fmaxf(m, om);
    ssum = ssum * __expf(m - nm) + os * __expf(om - nm);
    m = nm;
  }
  if (lane == 0) {
    float y = s + out_b[tgt];
    float lse = m + logf(ssum);
    float valid = (targets_len[b] > i + 1) ? 1.f : 0.f;
    term[row] = valid * (y - lse);
  }
}

__global__ void final_sum(const float* __restrict__ term, float* __restrict__ out) {
  __shared__ float red[256];
  float s = 0.f;
  for (int r = threadIdx.x; r < 2016; r += 256) s += term[r];
  red[threadIdx.x] = s;
  __syncthreads();
  for (int st = 128; st; st >>= 1) {
    if ((int)threadIdx.x < st) red[threadIdx.x] += red[threadIdx.x + st];
    __syncthreads();
  }
  if (threadIdx.x == 0) out[0] = -red[0];
}

// ---------------------------------------------------------------------------
extern "C" void kernel_launch(void* const* d_in, const int* in_sizes, int n_in,
                              void* d_out, int out_size, void* d_ws, size_t ws_size,
                              hipStream_t stream) {
  const int*   targets     = (const int*)d_in[0];
  const int*   targets_kws = (const int*)d_in[1];
  const float* sent_state  = (const float*)d_in[2];
  const int*   targets_len = (const int*)d_in[3];
  const float* emb_W       = (const float*)d_in[4];
  const float* w_Wih       = (const float*)d_in[5];
  const float* w_Whh       = (const float*)d_in[6];
  const float* w_bih       = (const float*)d_in[7];
  const float* w_bhh       = (const float*)d_in[8];
  const float* s_Wih       = (const float*)d_in[9];
  const float* s_Whh       = (const float*)d_in[10];
  const float* s_bih       = (const float*)d_in[11];
  const float* s_bhh       = (const float*)d_in[12];
  const float* out_W       = (const float*)d_in[13];
  const float* out_b       = (const float*)d_in[14];

  char* base = (char*)d_ws;
  size_t off = 0;
  auto alloc = [&](size_t bytes) -> void* {
    void* r = base + off;
    off += (bytes + 255) & ~(size_t)255;
    return r;
  };
  unsigned short* outWb   = (unsigned short*)alloc(32000ull * 1024 * 2);
  unsigned short* WihB    = (unsigned short*)alloc(3072ull * 1024 * 2);
  unsigned short* WhhB    = (unsigned short*)alloc(3072ull * 1024 * 2);
  unsigned short* sWihB   = (unsigned short*)alloc(3072ull * 1024 * 2);
  unsigned short* sWhhB   = (unsigned short*)alloc(3072ull * 1024 * 2);
  unsigned short* Xb      = (unsigned short*)alloc(2048ull * 1024 * 2);
  float*          Gi      = (float*)alloc(2048ull * 3072 * 4);
  unsigned short* WH      = (unsigned short*)alloc(2048ull * 1024 * 2);
  unsigned short* h_bf    = (unsigned short*)alloc(2 * 32ull * 1024 * 2);
  unsigned short* sent_bf = (unsigned short*)alloc(2 * 32ull * 1024 * 2);
  float2*         parts   = (float2*)alloc(2048ull * 125 * 8);
  float*          term    = (float*)alloc(2048ull * 4);
  unsigned*       flags   = (unsigned*)alloc(8192 * 4);   // [0..2047] recur, [2048..8191] gemm cvt
  unsigned*       gflags  = flags + 2048;

  zero_flags<<<32, 256, 0, stream>>>(flags, 8192);
  cvt4<<<3072, 256, 0, stream>>>(w_Wih, WihB, 786432);
  cvt4<<<3072, 256, 0, stream>>>(w_Whh, WhhB, 786432);
  cvt4<<<3072, 256, 0, stream>>>(s_Wih, sWihB, 786432);
  cvt4<<<3072, 256, 0, stream>>>(s_Whh, sWhhB, 786432);
  gatherx<<<2016, 256, 0, stream>>>(emb_W, targets, targets_kws, Xb);
  gemm_bt0<<<dim3(16, 24), 256, 0, stream>>>(Xb, WihB, Gi, 3072);

  fused_kernel<<<dim3(256), dim3(256), 0, stream>>>(
      Gi, WhhB, sWihB, sWhhB, h_bf, sent_bf, WH,
      w_bih, w_bhh, s_bih, s_bhh, targets, sent_state,
      flags, gflags, out_W, outWb, (float*)parts, out_b);

  row_loss<<<504, 256, 0, stream>>>(WH, outWb, out_b, targets, targets_len, parts, term);
  final_sum<<<1, 256, 0, stream>>>(term, (float*)d_out);
}

// Round 8
// 725.892 us; speedup vs baseline: 1.4790x; 1.0641x over previous
//
#include <hip/hip_runtime.h>

typedef __attribute__((ext_vector_type(8))) short short8;
typedef __attribute__((ext_vector_type(4))) float float4v;
typedef __attribute__((ext_vector_type(4))) unsigned short ushort4v;

#define DEV __device__ __forceinline__
#define AGENT __HIP_MEMORY_SCOPE_AGENT

DEV unsigned short f2bf(float f) {
  union { float f; unsigned u; } v; v.f = f;
  unsigned r = v.u + 0x7fffu + ((v.u >> 16) & 1u);
  return (unsigned short)(r >> 16);
}
DEV float bf2f(unsigned short h) {
  union { unsigned u; float f; } v; v.u = ((unsigned)h) << 16;
  return v.f;
}

// async global->LDS, 16B per lane; LDS dest is wave-uniform base + lane*16
DEV void gl2lds16(const void* g, void* l) {
  __builtin_amdgcn_global_load_lds(
      (const __attribute__((address_space(1))) void*)g,
      (__attribute__((address_space(3))) void*)l, 16, 0, 0);
}

// --- cross-workgroup data movement: LLC write-through / bypass ------------
DEV void ast32(unsigned short* p, unsigned v) {
  __hip_atomic_store((unsigned*)p, v, __ATOMIC_RELAXED, AGENT);
}
DEV short8 ald16(const unsigned short* p) {
  unsigned long long lo = __hip_atomic_load((const unsigned long long*)p,     __ATOMIC_RELAXED, AGENT);
  unsigned long long hi = __hip_atomic_load((const unsigned long long*)p + 1, __ATOMIC_RELAXED, AGENT);
  union { unsigned long long q[2]; short8 s; } u;
  u.q[0] = lo; u.q[1] = hi;
  return u.s;
}

// Grid barrier without RMW: wg stores flags[wg]=epoch (own cacheline);
// wave0's 64 lanes each poll one wg's flag, __all across the wave.
DEV void bar(unsigned* flags, unsigned epoch) {
  __syncthreads();
  if (threadIdx.x < 64) {
    const int lane = threadIdx.x;
    if (lane == 0)
      __hip_atomic_store(&flags[blockIdx.x * 32], epoch, __ATOMIC_RELAXED, AGENT);
    bool ok = false;
    do {
      ok = ok || (__hip_atomic_load(&flags[lane * 32], __ATOMIC_RELAXED, AGENT) >= epoch);
    } while (!__all(ok));
  }
  __syncthreads();
}

__global__ __launch_bounds__(256) void zero_flags(unsigned* p, int n) {
  int i = blockIdx.x * 256 + threadIdx.x;
  if (i < n) p[i] = 0;
}

// ---------------------------------------------------------------------------
// fp32 -> bf16 convert, 4 elems/thread
__global__ __launch_bounds__(256) void cvt4(const float* __restrict__ in,
                                            unsigned short* __restrict__ out, int n4) {
  const int idx = blockIdx.x * 256 + threadIdx.x;
  if (idx >= n4) return;
  float4 v = ((const float4*)in)[idx];
  ushort4v o = { f2bf(v.x), f2bf(v.y), f2bf(v.z), f2bf(v.w) };
  ((ushort4v*)out)[idx] = o;
}

// ---------------------------------------------------------------------------
// Gather X[row] = [emb(kw_{i+1}) | emb(lw_i)] as bf16, row = i*32+b
__global__ __launch_bounds__(256) void gatherx(const float* __restrict__ emb,
                                               const int* __restrict__ targets,
                                               const int* __restrict__ tkws,
                                               unsigned short* __restrict__ X) {
  const int row = blockIdx.x;
  const int i = row >> 5, b = row & 31;
  const int t = threadIdx.x;
  const int kw = tkws[b * 64 + i + 1];
  const int lw = targets[b * 64 + i];
  const float4* src = (t < 128) ? (const float4*)(emb + (size_t)kw * 512)
                                : (const float4*)(emb + (size_t)lw * 512);
  const int c = t & 127;
  float4 v = src[c];
  ushort4v o = { f2bf(v.x), f2bf(v.y), f2bf(v.z), f2bf(v.w) };
  ((ushort4v*)(X + (size_t)row * 1024))[(t < 128 ? 0 : 128) + c] = o;
}

// ---------------------------------------------------------------------------
// C = A[M,1024] * B[N,1024]^T, 128x128 tile, BK=32, bf16 MFMA 16x16x32.
// fp32 C store (used for the Gi pre-GEMM only).
__global__ __launch_bounds__(256, 1) void gemm_bt0(
    const unsigned short* __restrict__ A,
    const unsigned short* __restrict__ B,
    float* __restrict__ out,
    int ldc) {
  __shared__ __align__(16) unsigned short As[128 * 32];
  __shared__ __align__(16) unsigned short Bs[128 * 32];
  const int tid = threadIdx.x;
  const int w = tid >> 6, lane = tid & 63;
  const int r4 = lane >> 2, c4 = lane & 3;
  const int m0 = blockIdx.x * 128, n0 = blockIdx.y * 128;
  const int m_off = (w & 1) * 64, n_off = (w >> 1) * 64;
  const int lrow = lane & 15, lk = (lane >> 4) * 8;

  const unsigned short* Ab = A + (size_t)(m0 + w * 16 + r4) * 1024 + c4 * 8;
  const unsigned short* Bb = B + (size_t)(n0 + w * 16 + r4) * 1024 + c4 * 8;

  float4v acc[4][4] = {};

  for (int k0 = 0; k0 < 1024; k0 += 32) {
    gl2lds16(Ab + k0,             &As[w * 512]);
    gl2lds16(Ab + 64 * 1024 + k0, &As[2048 + w * 512]);
    gl2lds16(Bb + k0,             &Bs[w * 512]);
    gl2lds16(Bb + 64 * 1024 + k0, &Bs[2048 + w * 512]);
    __syncthreads();
    short8 af[4], bfr[4];
#pragma unroll
    for (int t = 0; t < 4; t++) {
      af[t]  = *(const short8*)&As[(m_off + t * 16 + lrow) * 32 + lk];
      bfr[t] = *(const short8*)&Bs[(n_off + t * 16 + lrow) * 32 + lk];
    }
#pragma unroll
    for (int mt = 0; mt < 4; mt++)
#pragma unroll
      for (int nt = 0; nt < 4; nt++)
        acc[mt][nt] = __builtin_amdgcn_mfma_f32_16x16x32_bf16(af[mt], bfr[nt], acc[mt][nt], 0, 0, 0);
    __syncthreads();
  }

#pragma unroll
  for (int mt = 0; mt < 4; mt++) {
    const int gr = m0 + m_off + mt * 16 + (lane >> 4) * 4;
#pragma unroll
    for (int nt = 0; nt < 4; nt++) {
      const int gc = n0 + n_off + nt * 16 + lrow;
#pragma unroll
      for (int rg = 0; rg < 4; rg++)
        out[(size_t)(gr + rg) * ldc + gc] = acc[mt][nt][rg];
    }
  }
}

// ---------------------------------------------------------------------------
// Fused kernel, NORMAL launch, grid 256 x 256thr, 1 wg/CU (117KB LDS).
//   wgs 0..63   : recurrence (identical to the R6/R7-passing structure).
//   wgs 64..255 : out_W cvt -> barrier -> logits GEMM, 128x256 tiles
//                 (2000 tiles), BK=32, double-buffered LDS with COUNTED
//                 vmcnt(6) (T4): the prefetch issued each K-step stays in
//                 flight across both raw s_barriers; __syncthreads (which
//                 drains vmcnt to 0, killing the pipeline - R7's flaw) is
//                 not used inside the K-loop. Each wave issues exactly 6
//                 global_load_lds per STAGE; in-order vmcnt retirement
//                 makes vmcnt(6) == "current buffer landed".
// Visibility model unchanged from R6 (proven).
__global__ __launch_bounds__(256, 1) void fused_kernel(
    const float* __restrict__ Gi,
    const unsigned short* __restrict__ WhhB,
    const unsigned short* __restrict__ sWihB,
    const unsigned short* __restrict__ sWhhB,
    unsigned short* __restrict__ h_bf,      // 2 x 32768 u16
    unsigned short* __restrict__ sent_bf,   // 2 x 32768 u16
    unsigned short* __restrict__ WH,
    const float* __restrict__ w_bih, const float* __restrict__ w_bhh,
    const float* __restrict__ s_bih, const float* __restrict__ s_bhh,
    const int* __restrict__ targets,
    const float* __restrict__ sent_state,
    unsigned* __restrict__ flags,           // [64*32] recur epochs
    unsigned* __restrict__ gflags,          // [192*32] cvt barrier
    const float* __restrict__ outW,
    unsigned short* __restrict__ outWb,
    float* __restrict__ parts,              // float2 [2048][125]
    const float* __restrict__ out_b) {
  __shared__ __align__(16) unsigned char smem[117248];
  const int tid = threadIdx.x;
  const int lane = tid & 63, wv = tid >> 6;

  // per-wave "any EOS at step i" bitmask (grid-uniform, both sides need it)
  unsigned long long eosmask;
  {
    bool e = false;
    if (lane < 63)
      for (int b = 0; b < 32; b++) e |= (targets[b * 64 + lane + 1] == 1);
    eosmask = __ballot(e);
  }

  if (blockIdx.x >= 64) {
    // ==================== GEMM side (192 wgs) ====================
    const int wg = blockIdx.x - 64;
    unsigned short* As0 = (unsigned short*)smem;             // 2 x 8 KB
    unsigned short* Bs0 = (unsigned short*)(smem + 16384);   // 2 x 16 KB
    float*          msb = (float*)(smem + 49152);            // 2 KB [2][128][2]

    // (a) out_W -> bf16, write-through so other XCDs see it
    for (int idx = wg * 256 + tid; idx < 8192000; idx += 192 * 256) {
      float4 v = ((const float4*)outW)[idx];
      unsigned p0 = (unsigned)f2bf(v.x) | ((unsigned)f2bf(v.y) << 16);
      unsigned p1 = (unsigned)f2bf(v.z) | ((unsigned)f2bf(v.w) << 16);
      unsigned long long pq = (unsigned long long)p0 | ((unsigned long long)p1 << 32);
      __hip_atomic_store((unsigned long long*)&outWb[(size_t)idx * 4], pq,
                         __ATOMIC_RELAXED, AGENT);
    }
    // (b) one-shot barrier among the 192 GEMM wgs
    __syncthreads();                       // drains the write-through stores
    if (tid == 0)
      __hip_atomic_store(&gflags[wg * 32], 1u, __ATOMIC_RELAXED, AGENT);
    if (tid < 64) {
      bool o0 = false, o1 = false, o2 = false;
      while (true) {
        o0 = o0 || (__hip_atomic_load(&gflags[tid * 32],         __ATOMIC_RELAXED, AGENT) != 0u);
        o1 = o1 || (__hip_atomic_load(&gflags[(64 + tid) * 32],  __ATOMIC_RELAXED, AGENT) != 0u);
        o2 = o2 || (__hip_atomic_load(&gflags[(128 + tid) * 32], __ATOMIC_RELAXED, AGENT) != 0u);
        if (__all(o0 && o1 && o2)) break;
        __builtin_amdgcn_s_sleep(32);
      }
    }
    __syncthreads();

    // (c) logits GEMM, 2000 tiles (16 mt x 125 nt), m-major grid-stride
    const int w = wv;
    const int r4 = lane >> 2, c4 = lane & 3;
    const int lrow = lane & 15, lk = (lane >> 4) * 8;
    const int m_off = (w & 1) * 64, n_off = (w >> 1) * 128;
    int gated_mt = -1;
    for (int bi = wg; bi < 2000; bi += 192) {
      const int mt = bi / 125, nt = bi - mt * 125;
      if (mt > gated_mt) {
        const int L = (4 * mt + 3 > 62) ? 62 : (4 * mt + 3);
        const unsigned E = 2u + (unsigned)L +
            (unsigned)__popcll(eosmask & ((1ull << L) - 1ull));
        if (tid < 64) {
          bool ok = false;
          while (true) {
            ok = ok || (__hip_atomic_load(&flags[tid * 32], __ATOMIC_RELAXED, AGENT) >= E);
            if (__all(ok)) break;
            __builtin_amdgcn_s_sleep(32);
          }
        }
        __syncthreads();
        gated_mt = mt;
      }
      const int m0 = mt * 128, n0 = nt * 256;
      const unsigned short* Ab = WH    + (size_t)(m0 + w * 16 + r4) * 1024 + c4 * 8;
      const unsigned short* Bb = outWb + (size_t)(n0 + w * 16 + r4) * 1024 + c4 * 8;
      float4v acc[4][8] = {};

      // per-wave: exactly 6 global_load_lds per STAGE (vmcnt counting!)
#define STAGE(buf, k0)                                                        \
      {                                                                       \
        unsigned short* A_ = As0 + (buf) * 4096;                              \
        unsigned short* B_ = Bs0 + (buf) * 8192;                              \
        gl2lds16(Ab + (k0),              A_ + (w * 16) * 32);                 \
        gl2lds16(Ab + 64 * 1024 + (k0),  A_ + (64 + w * 16) * 32);            \
        gl2lds16(Bb + (k0),              B_ + (w * 16) * 32);                 \
        gl2lds16(Bb + 64 * 1024 + (k0),  B_ + (64 + w * 16) * 32);            \
        gl2lds16(Bb + 128 * 1024 + (k0), B_ + (128 + w * 16) * 32);           \
        gl2lds16(Bb + 192 * 1024 + (k0), B_ + (192 + w * 16) * 32);           \
      }

      int cur = 0;
      STAGE(0, 0)
      for (int t = 0; t < 32; ++t) {
        if (t < 31) {
          STAGE(cur ^ 1, (t + 1) * 32)
          // wait ONLY for the current buffer's 6 loads; prefetch stays live
          asm volatile("s_waitcnt vmcnt(6)\n\ts_barrier" ::: "memory");
        } else {
          asm volatile("s_waitcnt vmcnt(0)\n\ts_barrier" ::: "memory");
        }
        __builtin_amdgcn_sched_barrier(0);
        const unsigned short* A_ = As0 + cur * 4096;
        const unsigned short* B_ = Bs0 + cur * 8192;
        short8 af[4], bfr[8];
#pragma unroll
        for (int x = 0; x < 4; x++)
          af[x] = *(const short8*)&A_[(m_off + x * 16 + lrow) * 32 + lk];
#pragma unroll
        for (int y = 0; y < 8; y++)
          bfr[y] = *(const short8*)&B_[(n_off + y * 16 + lrow) * 32 + lk];
#pragma unroll
        for (int a = 0; a < 4; a++)
#pragma unroll
          for (int b = 0; b < 8; b++)
            acc[a][b] = __builtin_amdgcn_mfma_f32_16x16x32_bf16(af[a], bfr[b], acc[a][b], 0, 0, 0);
        __builtin_amdgcn_sched_barrier(0);
        // WAR fence: all waves done reading 'cur' before next STAGE overwrites
        asm volatile("s_barrier" ::: "memory");
        cur ^= 1;
      }
#undef STAGE

      // epilogue: bias + per-row (max, sum-exp) over this 256-col tile
      float b8v[8];
#pragma unroll
      for (int b = 0; b < 8; b++) b8v[b] = out_b[n0 + n_off + b * 16 + lrow];
#pragma unroll
      for (int a = 0; a < 4; a++) {
#pragma unroll
        for (int rg = 0; rg < 4; rg++) {
          float vv[8];
#pragma unroll
          for (int b = 0; b < 8; b++) vv[b] = acc[a][b][rg] + b8v[b];
          float mx = vv[0];
#pragma unroll
          for (int b = 1; b < 8; b++) mx = fmaxf(mx, vv[b]);
#pragma unroll
          for (int d = 1; d < 16; d <<= 1) mx = fmaxf(mx, __shfl_xor(mx, d, 64));
          float s = 0.f;
#pragma unroll
          for (int b = 0; b < 8; b++) s += __expf(vv[b] - mx);
#pragma unroll
          for (int d = 1; d < 16; d <<= 1) s += __shfl_xor(s, d, 64);
          if ((lane & 15) == 0) {
            int r = m_off + a * 16 + (lane >> 4) * 4 + rg;
            msb[(w >> 1) * 256 + r * 2 + 0] = mx;
            msb[(w >> 1) * 256 + r * 2 + 1] = s;
          }
        }
      }
      __syncthreads();
      if (tid < 128) {
        float m1 = msb[tid * 2], s1 = msb[tid * 2 + 1];
        float m2 = msb[256 + tid * 2], s2 = msb[256 + tid * 2 + 1];
        float M = fmaxf(m1, m2);
        float S = s1 * __expf(m1 - M) + s2 * __expf(m2 - M);
        ((float2*)parts)[(size_t)(m0 + tid) * 125 + nt] = make_float2(M, S);
      }
      __syncthreads();
    }
    return;
  }

  // ==================== recur side (64 wgs) ====================
  unsigned short* WhhS = (unsigned short*)smem;                  // 96 KB
  float (*Cred)[32][49] = (float (*)[32][49])(smem + 98304);     // 12544 B
  float (*hsl)[16] = (float (*)[16])(smem + 110848);             // 2 KB
  float (*ssl)[16] = (float (*)[16])(smem + 112896);             // 2 KB
  float (*whsl)[16] = (float (*)[16])(smem + 114944);            // 2 KB

  const int khalf = wv >> 1, mtile = wv & 1;
  const int jb = blockIdx.x * 16;
  const int lr = lane & 15;
  const int bb = mtile * 16 + lr;
  const int kb = khalf * 512 + (lane >> 4) * 8;
  const int cb = kb >> 3;          // 16B-chunk base within row
  const int swz = lr & 7;
  const int b0 = (tid * 2) >> 4, j0 = (tid * 2) & 15;
  unsigned epoch = 0;
  int scur = 0;

  // ---- one-time: Whh wg-slice -> LDS, XOR-swizzled 16B chunks ----
  for (int idx = tid; idx < 6144; idx += 256) {
    const int R = idx >> 7, c = idx & 127;     // R = g*16+rr, c = chunk
    const int g = R >> 4, rr = R & 15;
    short8 v = *(const short8*)&WhhB[((size_t)(g * 1024 + jb + rr)) * 1024 + c * 8];
    *(short8*)&WhhS[(R * 128 + (c ^ (rr & 7))) * 8] = v;
  }

  // ---- one-time: biases for this thread's 2 elements ----
  float bi[2][3], bh[2][3];
#pragma unroll
  for (int u = 0; u < 2; u++)
#pragma unroll
    for (int g = 0; g < 3; g++) {
      bi[u][g] = w_bih[g * 1024 + jb + j0 + u];
      bh[u][g] = w_bhh[g * 1024 + jb + j0 + u];
    }

  // ---- init state, publish to buffer 0 ----
  {
    float v0 = sent_state[b0 * 1024 + jb + j0];
    float v1 = sent_state[b0 * 1024 + jb + j0 + 1];
    hsl[b0][j0] = v0; hsl[b0][j0 + 1] = v1;
    ssl[b0][j0] = v0; ssl[b0][j0 + 1] = v1;
    unsigned pv = (unsigned)f2bf(v0) | ((unsigned)f2bf(v1) << 16);
    ast32(&h_bf[b0 * 1024 + jb + j0], pv);
    ast32(&sent_bf[b0 * 1024 + jb + j0], pv);
  }

  // ---- Gi prefetch for step 0 ----
  float2 gp[3];
  {
    const float* p = Gi + (size_t)b0 * 3072 + jb + j0;
    gp[0] = *(const float2*)(p);
    gp[1] = *(const float2*)(p + 1024);
    gp[2] = *(const float2*)(p + 2048);
  }

  epoch++; bar(flags, epoch);

  for (int i = 0; i < 63; i++) {
    const unsigned short* hr = h_bf + (i & 1) * 32768;
    unsigned short*       hw = h_bf + ((i + 1) & 1) * 32768;
    const bool anyeos = (eosmask >> i) & 1;

    // gh = h @ Whh^T  (A from LLC, B from LDS); batch-issue coherent loads
    short8 a[16];
#pragma unroll
    for (int ks = 0; ks < 16; ks++)
      a[ks] = ald16(&hr[bb * 1024 + kb + ks * 32]);
    float4v acc[3] = {};
#pragma unroll
    for (int ks = 0; ks < 16; ks++) {
#pragma unroll
      for (int g = 0; g < 3; g++) {
        short8 b8 = *(const short8*)&WhhS[((g * 16 + lr) * 128 + ((cb + ks * 4) ^ swz)) * 8];
        acc[g] = __builtin_amdgcn_mfma_f32_16x16x32_bf16(a[ks], b8, acc[g], 0, 0, 0);
      }
    }
#pragma unroll
    for (int g = 0; g < 3; g++)
#pragma unroll
      for (int rg = 0; rg < 4; rg++)
        Cred[khalf][mtile * 16 + (lane >> 4) * 4 + rg][g * 16 + lr] = acc[g][rg];
    __syncthreads();

    float wh2[2];
#pragma unroll
    for (int u = 0; u < 2; u++) {
      const int jj = j0 + u;
      float ghr = Cred[0][b0][jj]      + Cred[1][b0][jj]      + bh[u][0];
      float ghz = Cred[0][b0][16 + jj] + Cred[1][b0][16 + jj] + bh[u][1];
      float ghn = Cred[0][b0][32 + jj] + Cred[1][b0][32 + jj] + bh[u][2];
      float gir = ((float*)&gp[0])[u] + bi[u][0];
      float giz = ((float*)&gp[1])[u] + bi[u][1];
      float gin = ((float*)&gp[2])[u] + bi[u][2];
      float r = 1.f / (1.f + __expf(-(gir + ghr)));
      float z = 1.f / (1.f + __expf(-(giz + ghz)));
      float n = tanhf(gin + r * ghn);
      float wh = (1.f - z) * n + z * hsl[b0][jj];
      whsl[b0][jj] = wh;
      wh2[u] = wh;
    }
    {
      unsigned pv = (unsigned)f2bf(wh2[0]) | ((unsigned)f2bf(wh2[1]) << 16);
      ast32(&WH[(size_t)(i * 32 + b0) * 1024 + jb + j0], pv);
    }

    // Gi prefetch for next step (independent of barrier)
    if (i < 62) {
      const float* p = Gi + (size_t)((i + 1) * 32 + b0) * 3072 + jb + j0;
      gp[0] = *(const float2*)(p);
      gp[1] = *(const float2*)(p + 1024);
      gp[2] = *(const float2*)(p + 2048);
    }

    if (!anyeos) {
      hsl[b0][j0] = wh2[0]; hsl[b0][j0 + 1] = wh2[1];
      unsigned pv = (unsigned)f2bf(wh2[0]) | ((unsigned)f2bf(wh2[1]) << 16);
      ast32(&hw[b0 * 1024 + jb + j0], pv);
      epoch++; bar(flags, epoch);
    } else {
      epoch++; bar(flags, epoch);   // WH[i] visible grid-wide
      const unsigned short* sr = sent_bf + scur * 32768;
      unsigned short*       sw = sent_bf + (scur ^ 1) * 32768;
      // gi_s = wh @ sWih^T  (batch-issued coherent A-loads)
      short8 a2[16];
#pragma unroll
      for (int ks = 0; ks < 16; ks++)
        a2[ks] = ald16(&WH[(size_t)(i * 32 + bb) * 1024 + kb + ks * 32]);
      float4v acc2[3] = {};
#pragma unroll
      for (int ks = 0; ks < 16; ks++) {
#pragma unroll
        for (int g = 0; g < 3; g++) {
          short8 b8 = *(const short8*)&sWihB[(size_t)(g * 1024 + jb + lr) * 1024 + kb + ks * 32];
          acc2[g] = __builtin_amdgcn_mfma_f32_16x16x32_bf16(a2[ks], b8, acc2[g], 0, 0, 0);
        }
      }
#pragma unroll
      for (int g = 0; g < 3; g++)
#pragma unroll
        for (int rg = 0; rg < 4; rg++)
          Cred[khalf][mtile * 16 + (lane >> 4) * 4 + rg][g * 16 + lr] = acc2[g][rg];
      __syncthreads();
      float gis[2][3];
#pragma unroll
      for (int u = 0; u < 2; u++) {
        const int jj = j0 + u;
#pragma unroll
        for (int g = 0; g < 3; g++)
          gis[u][g] = Cred[0][b0][g * 16 + jj] + Cred[1][b0][g * 16 + jj] + s_bih[g * 1024 + jb + jj];
      }
      __syncthreads();
      // gh_s = sent @ sWhh^T  (batch-issued coherent A-loads)
      short8 a3[16];
#pragma unroll
      for (int ks = 0; ks < 16; ks++)
        a3[ks] = ald16(&sr[bb * 1024 + kb + ks * 32]);
      float4v acc3[3] = {};
#pragma unroll
      for (int ks = 0; ks < 16; ks++) {
#pragma unroll
        for (int g = 0; g < 3; g++) {
          short8 b8 = *(const short8*)&sWhhB[(size_t)(g * 1024 + jb + lr) * 1024 + kb + ks * 32];
          acc3[g] = __builtin_amdgcn_mfma_f32_16x16x32_bf16(a3[ks], b8, acc3[g], 0, 0, 0);
        }
      }
#pragma unroll
      for (int g = 0; g < 3; g++)
#pragma unroll
        for (int rg = 0; rg < 4; rg++)
          Cred[khalf][mtile * 16 + (lane >> 4) * 4 + rg][g * 16 + lr] = acc3[g][rg];
      __syncthreads();
      float ns2[2], nw2[2];
#pragma unroll
      for (int u = 0; u < 2; u++) {
        const int jj = j0 + u;
        float shr = Cred[0][b0][jj]      + Cred[1][b0][jj]      + s_bhh[jb + jj];
        float shz = Cred[0][b0][16 + jj] + Cred[1][b0][16 + jj] + s_bhh[1024 + jb + jj];
        float shn = Cred[0][b0][32 + jj] + Cred[1][b0][32 + jj] + s_bhh[2048 + jb + jj];
        float r = 1.f / (1.f + __expf(-(gis[u][0] + shr)));
        float z = 1.f / (1.f + __expf(-(gis[u][1] + shz)));
        float n = tanhf(gis[u][2] + r * shn);
        float s_old = ssl[b0][jj];
        float tmp = (1.f - z) * n + z * s_old;
        bool m = (targets[b0 * 64 + i + 1] == 1);
        ns2[u] = m ? tmp : s_old;
        nw2[u] = m ? tmp : whsl[b0][jj];
        ssl[b0][jj] = ns2[u];
        hsl[b0][jj] = nw2[u];
      }
      unsigned pvs = (unsigned)f2bf(ns2[0]) | ((unsigned)f2bf(ns2[1]) << 16);
      unsigned pvh = (unsigned)f2bf(nw2[0]) | ((unsigned)f2bf(nw2[1]) << 16);
      ast32(&sw[b0 * 1024 + jb + j0], pvs);
      ast32(&hw[b0 * 1024 + jb + j0], pvh);
      scur ^= 1;
      epoch++; bar(flags, epoch);
    }
  }
}

// ---------------------------------------------------------------------------
// Per row: y = WH[row].outW[tgt] + out_b[tgt]; lse from 125 (m,s) partials;
// term = valid * (y - lse). One wave per row.
__global__ __launch_bounds__(256) void row_loss(
    const unsigned short* __restrict__ WH,
    const unsigned short* __restrict__ outWb,
    const float* __restrict__ out_b,
    const int* __restrict__ targets,
    const int* __restrict__ targets_len,
    const float2* __restrict__ partials,
    float* __restrict__ term) {
  const int wv = threadIdx.x >> 6, lane = threadIdx.x & 63;
  const int row = blockIdx.x * 4 + wv;
  const int b = row & 31, i = row >> 5;
  const int tgt = targets[b * 64 + i + 1];
  const short8* a8 = (const short8*)(WH + (size_t)row * 1024);
  const short8* w8 = (const short8*)(outWb + (size_t)tgt * 1024);
  float s = 0.f;
#pragma unroll
  for (int c = 0; c < 2; c++) {
    short8 av = a8[lane + 64 * c];
    short8 wv8 = w8[lane + 64 * c];
#pragma unroll
    for (int j = 0; j < 8; j++)
      s += bf2f((unsigned short)av[j]) * bf2f((unsigned short)wv8[j]);
  }
#pragma unroll
  for (int d = 32; d; d >>= 1) s += __shfl_xor(s, d, 64);

  float m = -1e30f, ssum = 0.f;
  for (int vt = lane; vt < 125; vt += 64) {
    float2 pp = partials[(size_t)row * 125 + vt];
    float nm = fmaxf(m, pp.x);
    ssum = ssum * __expf(m - nm) + pp.y * __expf(pp.x - nm);
    m = nm;
  }
#pragma unroll
  for (int d = 32; d; d >>= 1) {
    float om = __shfl_xor(m, d, 64);
    float os = __shfl_xor(ssum, d, 64);
    float nm = fmaxf(m, om);
    ssum = ssum * __expf(m - nm) + os * __expf(om - nm);
    m = nm;
  }
  if (lane == 0) {
    float y = s + out_b[tgt];
    float lse = m + logf(ssum);
    float valid = (targets_len[b] > i + 1) ? 1.f : 0.f;
    term[row] = valid * (y - lse);
  }
}

__global__ void final_sum(const float* __restrict__ term, float* __restrict__ out) {
  __shared__ float red[256];
  float s = 0.f;
  for (int r = threadIdx.x; r < 2016; r += 256) s += term[r];
  red[threadIdx.x] = s;
  __syncthreads();
  for (int st = 128; st; st >>= 1) {
    if ((int)threadIdx.x < st) red[threadIdx.x] += red[threadIdx.x + st];
    __syncthreads();
  }
  if (threadIdx.x == 0) out[0] = -red[0];
}

// ---------------------------------------------------------------------------
extern "C" void kernel_launch(void* const* d_in, const int* in_sizes, int n_in,
                              void* d_out, int out_size, void* d_ws, size_t ws_size,
                              hipStream_t stream) {
  const int*   targets     = (const int*)d_in[0];
  const int*   targets_kws = (const int*)d_in[1];
  const float* sent_state  = (const float*)d_in[2];
  const int*   targets_len = (const int*)d_in[3];
  const float* emb_W       = (const float*)d_in[4];
  const float* w_Wih       = (const float*)d_in[5];
  const float* w_Whh       = (const float*)d_in[6];
  const float* w_bih       = (const float*)d_in[7];
  const float* w_bhh       = (const float*)d_in[8];
  const float* s_Wih       = (const float*)d_in[9];
  const float* s_Whh       = (const float*)d_in[10];
  const float* s_bih       = (const float*)d_in[11];
  const float* s_bhh       = (const float*)d_in[12];
  const float* out_W       = (const float*)d_in[13];
  const float* out_b       = (const float*)d_in[14];

  char* base = (char*)d_ws;
  size_t off = 0;
  auto alloc = [&](size_t bytes) -> void* {
    void* r = base + off;
    off += (bytes + 255) & ~(size_t)255;
    return r;
  };
  unsigned short* outWb   = (unsigned short*)alloc(32000ull * 1024 * 2);
  unsigned short* WihB    = (unsigned short*)alloc(3072ull * 1024 * 2);
  unsigned short* WhhB    = (unsigned short*)alloc(3072ull * 1024 * 2);
  unsigned short* sWihB   = (unsigned short*)alloc(3072ull * 1024 * 2);
  unsigned short* sWhhB   = (unsigned short*)alloc(3072ull * 1024 * 2);
  unsigned short* Xb      = (unsigned short*)alloc(2048ull * 1024 * 2);
  float*          Gi      = (float*)alloc(2048ull * 3072 * 4);
  unsigned short* WH      = (unsigned short*)alloc(2048ull * 1024 * 2);
  unsigned short* h_bf    = (unsigned short*)alloc(2 * 32ull * 1024 * 2);
  unsigned short* sent_bf = (unsigned short*)alloc(2 * 32ull * 1024 * 2);
  float2*         parts   = (float2*)alloc(2048ull * 125 * 8);
  float*          term    = (float*)alloc(2048ull * 4);
  unsigned*       flags   = (unsigned*)alloc(8192 * 4);   // [0..2047] recur, [2048..8191] gemm cvt
  unsigned*       gflags  = flags + 2048;

  zero_flags<<<32, 256, 0, stream>>>(flags, 8192);
  cvt4<<<3072, 256, 0, stream>>>(w_Wih, WihB, 786432);
  cvt4<<<3072, 256, 0, stream>>>(w_Whh, WhhB, 786432);
  cvt4<<<3072, 256, 0, stream>>>(s_Wih, sWihB, 786432);
  cvt4<<<3072, 256, 0, stream>>>(s_Whh, sWhhB, 786432);
  gatherx<<<2016, 256, 0, stream>>>(emb_W, targets, targets_kws, Xb);
  gemm_bt0<<<dim3(16, 24), 256, 0, stream>>>(Xb, WihB, Gi, 3072);

  fused_kernel<<<dim3(256), dim3(256), 0, stream>>>(
      Gi, WhhB, sWihB, sWhhB, h_bf, sent_bf, WH,
      w_bih, w_bhh, s_bih, s_bhh, targets, sent_state,
      flags, gflags, out_W, outWb, (float*)parts, out_b);

  row_loss<<<504, 256, 0, stream>>>(WH, outWb, out_b, targets, targets_len, parts, term);
  final_sum<<<1, 256, 0, stream>>>(term, (float*)d_out);
}